// Round 1
// baseline (411.938 us; speedup 1.0000x reference)
//
#include <hip/hip_runtime.h>

// Round 16: re-bench after infra failure + exact defer-rescale in attn.
// alpha == 1.0 exactly when tile max <= running max; wave-uniform __any
// branch skips 4 v_exp + 20 mults per wave-tile in that case (bit-identical
// math). oacc rescale hoisted out of the PV loop. Everything else unchanged
// from the verified 413.6us kernel: 512-thread attn blocks (8 waves x 16
// q-rows), register-prefetched k-loop, kvproj with V pre-transpose, fp32
// I/O with bf16 MFMA compute.

#define B_  2
#define L_  4096
#define D_  512
#define H_  8
#define BH_ 16
#define M_  8192

typedef __attribute__((ext_vector_type(8))) short short8;    // 8 bf16 = 4 VGPR
typedef __attribute__((ext_vector_type(4))) float f32x4;
typedef unsigned short u16;

static __device__ __forceinline__ u16 f2b(float f) {
    union { float f; unsigned i; } x; x.f = f;
    unsigned r = x.i + 0x7fff + ((x.i >> 16) & 1);   // RNE
    return (u16)(r >> 16);
}

// Stage 8 consecutive fp32 -> 8 bf16 (16 B) into LDS.
static __device__ __forceinline__ void stage8f(u16* dst, const float* s) {
    const float4 a = *(const float4*)s;
    const float4 b = *(const float4*)(s + 4);
    u16 tmp[8] = { f2b(a.x), f2b(a.y), f2b(a.z), f2b(a.w),
                   f2b(b.x), f2b(b.y), f2b(b.z), f2b(b.w) };
    *(uint4*)dst = *(const uint4*)tmp;
}

// ---------------------------------------------------------------------------
// K/V projection. grid (chunk, L/64, 2) z=0->K (row-major L x 64),
// z=1->V (TRANSPOSED: 64 dims x L keys). Block 64x64 tile, 4 waves 2x2.
// ---------------------------------------------------------------------------
__global__ __launch_bounds__(256) void kvproj_kernel(
    const float* __restrict__ x,
    const float* __restrict__ Wk, const float* __restrict__ bk,
    const float* __restrict__ Wv, const float* __restrict__ bv,
    u16* __restrict__ Kws, u16* __restrict__ Vws, int bh0)
{
    __shared__ __align__(16) unsigned char sm[10240];
    u16 (*As)[40] = (u16(*)[40])sm;            // 5120 B
    u16 (*Bs)[40] = (u16(*)[40])(sm + 5120);   // 5120 B
    u16 (*Ts)[73] = (u16(*)[73])sm;            // 9344 B (V transpose bounce)

    const int t    = threadIdx.x;
    const int wid  = t >> 6, lane = t & 63;
    const int m15  = lane & 15, quad = lane >> 4;
    const int wm   = wid >> 1, wn = wid & 1;

    const int bh = bh0 + blockIdx.x;
    const int b  = bh >> 3, h = bh & 7;
    const int l0 = blockIdx.y * 64;
    const float* W  = blockIdx.z ? Wv : Wk;
    const float* bi = blockIdx.z ? bv : bk;

    const int lrow = t >> 2;        // 0..63
    const int lcol = (t & 3) * 8;   // 0,8,16,24
    const size_t xrow0 = (size_t)b * L_ + l0;

    f32x4 acc[2][2] = {};

    for (int k0 = 0; k0 < 512; k0 += 32) {
        __syncthreads();
        stage8f(&As[lrow][lcol], x + (xrow0 + lrow) * 512 + k0 + lcol);
        stage8f(&Bs[lrow][lcol], W + (size_t)(h * 64 + lrow) * 512 + k0 + lcol);
        __syncthreads();

        short8 afr[2], bfr[2];
#pragma unroll
        for (int mi = 0; mi < 2; ++mi)
            afr[mi] = *(const short8*)(&As[wm * 32 + mi * 16 + m15][quad * 8]);
#pragma unroll
        for (int ni = 0; ni < 2; ++ni)
            bfr[ni] = *(const short8*)(&Bs[wn * 32 + ni * 16 + m15][quad * 8]);
#pragma unroll
        for (int mi = 0; mi < 2; ++mi)
#pragma unroll
            for (int ni = 0; ni < 2; ++ni)
                acc[mi][ni] = __builtin_amdgcn_mfma_f32_16x16x32_bf16(
                    afr[mi], bfr[ni], acc[mi][ni], 0, 0, 0);
    }

    if (blockIdx.z == 0) {
        u16* out = Kws + (size_t)blockIdx.x * (L_ * 64);
#pragma unroll
        for (int mi = 0; mi < 2; ++mi)
#pragma unroll
            for (int ni = 0; ni < 2; ++ni) {
                const int d  = wn * 32 + ni * 16 + m15;
                const float bv_ = bi[h * 64 + d];
#pragma unroll
                for (int r = 0; r < 4; ++r) {
                    const int l = l0 + wm * 32 + mi * 16 + quad * 4 + r;
                    out[(size_t)l * 64 + d] = f2b(acc[mi][ni][r] + bv_);
                }
            }
    } else {
        __syncthreads();   // all MFMA LDS reads done before overwrite
#pragma unroll
        for (int mi = 0; mi < 2; ++mi)
#pragma unroll
            for (int ni = 0; ni < 2; ++ni) {
                const int d  = wn * 32 + ni * 16 + m15;
                const float bv_ = bi[h * 64 + d];
#pragma unroll
                for (int r = 0; r < 4; ++r)
                    Ts[wm * 32 + mi * 16 + quad * 4 + r][d] = f2b(acc[mi][ni][r] + bv_);
            }
        __syncthreads();
        u16* Vt = Vws + (size_t)blockIdx.x * ((size_t)64 * L_);
        const int d  = t >> 2;
        const int ls = (t & 3) * 16;
        u16 pk[16];
#pragma unroll
        for (int j = 0; j < 16; ++j) pk[j] = Ts[ls + j][d];
        u16* dst = Vt + (size_t)d * L_ + l0 + ls;
        *(uint4*)dst       = *(const uint4*)pk;
        *(uint4*)(dst + 8) = *(const uint4*)(pk + 8);
    }
}

// ---------------------------------------------------------------------------
// Fused Q-projection + flash attention. grid (L/128, chunk), block 512.
// 8 waves; wave w owns q-rows [16w, 16w+16). Register-prefetched k-loop.
// LDS phased union: ph1 {xs[128][40], wqs[64][40]} overlays ph2 {Ks, Vts}.
// ---------------------------------------------------------------------------
#define KS_OFF  0
#define VTS_OFF 9216
#define PS_OFF  18432
#define MS_OFF  36864
__global__ __launch_bounds__(512) void attn_kernel(
    const float* __restrict__ x,
    const float* __restrict__ Wq, const float* __restrict__ bq,
    const u16* __restrict__ Kws, const u16* __restrict__ Vws,
    const int* __restrict__ mask,
    float* __restrict__ O, int bh0)
{
    __shared__ __align__(16) unsigned char sm[36864 + 256];
    u16 (*xs)[40]  = (u16(*)[40])sm;                    // ph1, 10240 B
    u16 (*wqs)[40] = (u16(*)[40])(sm + 10240);          // ph1, 5120 B
    u16 (*Ks)[72]  = (u16(*)[72])(sm + KS_OFF);         // ph2, 9216 B [key][dim]
    u16 (*Vts)[72] = (u16(*)[72])(sm + VTS_OFF);        // ph2, 9216 B [dim][key]
    float* Ms      = (float*)(sm + MS_OFF);             // 1.0 = masked

    const int t    = threadIdx.x;
    const int wid  = t >> 6, lane = t & 63;
    const int m15  = lane & 15, quad = lane >> 4;
    u16 (*Psw)[72] = (u16(*)[72])(sm + PS_OFF + wid * (16 * 72 * 2));  // per-wave

    const int bh = bh0 + blockIdx.y;
    const int b  = bh >> 3, h = bh & 7;
    const int q0 = blockIdx.x * 128;
    const u16* Kc  = Kws + (size_t)blockIdx.y * (L_ * 64);
    const u16* Vtc = Vws + (size_t)blockIdx.y * ((size_t)64 * L_);

    // ---- phase 1: Q[128][64] = x[q-tile] @ Wq[h]^T + bq, pre-scaled 1/8 ----
    f32x4 qacc[4] = {};
    {
        const int xr = t >> 2, xc = (t & 3) * 8;         // 128 rows x 4 groups
        for (int k0 = 0; k0 < 512; k0 += 32) {
            __syncthreads();
            stage8f(&xs[xr][xc], x + ((size_t)b * L_ + q0 + xr) * 512 + k0 + xc);
            if (t < 256)
                stage8f(&wqs[xr][xc], Wq + (size_t)(h * 64 + xr) * 512 + k0 + xc);
            __syncthreads();
            const short8 afr = *(const short8*)(&xs[wid * 16 + m15][quad * 8]);
#pragma unroll
            for (int ni = 0; ni < 4; ++ni) {
                const short8 bfr = *(const short8*)(&wqs[ni * 16 + m15][quad * 8]);
                qacc[ni] = __builtin_amdgcn_mfma_f32_16x16x32_bf16(afr, bfr, qacc[ni], 0, 0, 0);
            }
        }
    }
    // C-layout -> per-wave Ps slice -> A-frag (wave-local, DS in-order)
    short8 qf[2];
#pragma unroll
    for (int ni = 0; ni < 4; ++ni) {
        const float bv_ = bq[h * 64 + ni * 16 + m15];
#pragma unroll
        for (int r = 0; r < 4; ++r)
            Psw[quad * 4 + r][ni * 16 + m15] = f2b((qacc[ni][r] + bv_) * 0.125f);
    }
#pragma unroll
    for (int kc = 0; kc < 2; ++kc)
        qf[kc] = *(const short8*)(&Psw[m15][kc * 32 + quad * 8]);

    // ---- flash loop over 64-key tiles, register-prefetched ----
    const int srow = t >> 3;            // 0..63
    const int scol = (t & 7) * 8;       // 0..56
    uint4 kreg = *(const uint4*)(Kc  + (size_t)srow * 64 + scol);
    uint4 vreg = *(const uint4*)(Vtc + (size_t)srow * L_ + scol);
    int   mreg = (t < 64) ? mask[b * L_ + t] : 0;

    float m_i[4], l_i[4];
#pragma unroll
    for (int r = 0; r < 4; ++r) { m_i[r] = -1e30f; l_i[r] = 0.0f; }
    f32x4 oacc[4] = {};

    for (int kt = 0; kt < 64; ++kt) {
        __syncthreads();                 // prior tile's LDS reads done
        *(uint4*)(&Ks [srow][scol]) = kreg;
        *(uint4*)(&Vts[srow][scol]) = vreg;
        if (t < 64) Ms[t] = (mreg == 0) ? 1.0f : 0.0f;
        __syncthreads();                 // tile kt visible
        if (kt + 1 < 64) {               // prefetch kt+1 (overlaps compute)
            const int k1 = (kt + 1) * 64;
            kreg = *(const uint4*)(Kc  + (size_t)(k1 + srow) * 64 + scol);
            vreg = *(const uint4*)(Vtc + (size_t)srow * L_ + k1 + scol);
            if (t < 64) mreg = mask[b * L_ + k1 + t];
        }

        // S = (Q/8) K^T, C-layout; masked -> -10000
        float s[4][4];
#pragma unroll
        for (int ni = 0; ni < 4; ++ni) {
            f32x4 sa = {};
#pragma unroll
            for (int kc = 0; kc < 2; ++kc) {
                const short8 kf = *(const short8*)(&Ks[ni * 16 + m15][kc * 32 + quad * 8]);
                sa = __builtin_amdgcn_mfma_f32_16x16x32_bf16(qf[kc], kf, sa, 0, 0, 0);
            }
            const float msk = Ms[ni * 16 + m15];
#pragma unroll
            for (int r = 0; r < 4; ++r)
                s[ni][r] = (msk != 0.0f) ? -10000.0f : sa[r];
        }

        // online softmax per q-row (16 lanes of a quad share a row).
        // Exact defer-rescale: alpha == 1.0 exactly when no row's tile-max
        // exceeds the running max -> skip exp + oacc/l rescale (bit-identical).
        float mx[4];
#pragma unroll
        for (int r = 0; r < 4; ++r) {
            float m0 = fmaxf(fmaxf(s[0][r], s[1][r]), fmaxf(s[2][r], s[3][r]));
#pragma unroll
            for (int off = 1; off < 16; off <<= 1)
                m0 = fmaxf(m0, __shfl_xor(m0, off));
            mx[r] = m0;
        }
        const bool grow = (mx[0] > m_i[0]) || (mx[1] > m_i[1]) ||
                          (mx[2] > m_i[2]) || (mx[3] > m_i[3]);
        if (__any(grow)) {
#pragma unroll
            for (int r = 0; r < 4; ++r) {
                const float mnew = fmaxf(m_i[r], mx[r]);
                const float a = __expf(m_i[r] - mnew);
                m_i[r] = mnew;
                l_i[r] *= a;
#pragma unroll
                for (int ni = 0; ni < 4; ++ni)
                    oacc[ni][r] *= a;
            }
        }
#pragma unroll
        for (int r = 0; r < 4; ++r) {
            float ss = 0.0f;
#pragma unroll
            for (int ni = 0; ni < 4; ++ni) {
                const float p = __expf(s[ni][r] - m_i[r]);
                s[ni][r] = p;
                ss += p;
            }
#pragma unroll
            for (int off = 1; off < 16; off <<= 1)
                ss += __shfl_xor(ss, off);
            l_i[r] += ss;
        }

        // P: C-layout -> per-wave Ps -> A-frags
#pragma unroll
        for (int ni = 0; ni < 4; ++ni)
#pragma unroll
            for (int r = 0; r < 4; ++r)
                Psw[quad * 4 + r][ni * 16 + m15] = f2b(s[ni][r]);
        short8 pf[2];
#pragma unroll
        for (int kc = 0; kc < 2; ++kc)
            pf[kc] = *(const short8*)(&Psw[m15][kc * 32 + quad * 8]);

        // O += P V (rescale already applied in the grow branch)
#pragma unroll
        for (int ni = 0; ni < 4; ++ni) {
#pragma unroll
            for (int kc = 0; kc < 2; ++kc) {
                const short8 vf = *(const short8*)(&Vts[ni * 16 + m15][kc * 32 + quad * 8]);
                oacc[ni] = __builtin_amdgcn_mfma_f32_16x16x32_bf16(pf[kc], vf, oacc[ni], 0, 0, 0);
            }
        }
    }

    // epilogue: O /= l -> fp32 (B, L, 512)
#pragma unroll
    for (int ni = 0; ni < 4; ++ni)
#pragma unroll
        for (int r = 0; r < 4; ++r) {
            const int qrow = q0 + wid * 16 + quad * 4 + r;
            O[((size_t)b * L_ + qrow) * 512 + h * 64 + ni * 16 + m15] =
                oacc[ni][r] / l_i[r];
        }
}

// ---------------------------------------------------------------------------
// In-place fp32 output projection: AO = AO @ Wo^T + bo, (M,512).
// ---------------------------------------------------------------------------
__global__ __launch_bounds__(256) void outproj_kernel(
    float* __restrict__ AO,
    const float* __restrict__ Wo, const float* __restrict__ bo)
{
    __shared__ __align__(16) u16 As[32][520];
    __shared__ __align__(16) u16 Ws_[64][40];

    const int t    = threadIdx.x;
    const int wid  = t >> 6, lane = t & 63;
    const int m15  = lane & 15, quad = lane >> 4;
    const int wm   = wid >> 1, wn = wid & 1;
    const int bm   = blockIdx.x * 32;

#pragma unroll
    for (int it = 0; it < 8; ++it) {
        const int idx = t + it * 256;            // 0..2047
        const int row = idx >> 6, c8 = (idx & 63) * 8;
        stage8f(&As[row][c8], AO + (size_t)(bm + row) * 512 + c8);
    }
    const int lrow = t >> 2;
    const int lcol = (t & 3) * 8;
    __syncthreads();

    for (int n0 = 0; n0 < 512; n0 += 64) {
        f32x4 acc[2] = {};
        for (int k0 = 0; k0 < 512; k0 += 32) {
            __syncthreads();
            stage8f(&Ws_[lrow][lcol], Wo + (size_t)(n0 + lrow) * 512 + k0 + lcol);
            __syncthreads();
            const short8 afr = *(const short8*)(&As[wm * 16 + m15][k0 + quad * 8]);
#pragma unroll
            for (int ni = 0; ni < 2; ++ni) {
                const short8 bfr = *(const short8*)(&Ws_[wn * 32 + ni * 16 + m15][quad * 8]);
                acc[ni] = __builtin_amdgcn_mfma_f32_16x16x32_bf16(afr, bfr, acc[ni], 0, 0, 0);
            }
        }
#pragma unroll
        for (int ni = 0; ni < 2; ++ni) {
            const int col = n0 + wn * 32 + ni * 16 + m15;
            const float bv_ = bo[col];
#pragma unroll
            for (int r = 0; r < 4; ++r) {
                const int row = bm + wm * 16 + quad * 4 + r;
                AO[(size_t)row * 512 + col] = acc[ni][r] + bv_;
            }
        }
    }
}

extern "C" void kernel_launch(void* const* d_in, const int* in_sizes, int n_in,
                              void* d_out, int out_size, void* d_ws, size_t ws_size,
                              hipStream_t stream) {
    const float* x    = (const float*)d_in[0];
    const int*   mask = (const int*)d_in[1];
    const float* Wq = (const float*)d_in[2]; const float* bq = (const float*)d_in[3];
    const float* Wk = (const float*)d_in[4]; const float* bk = (const float*)d_in[5];
    const float* Wv = (const float*)d_in[6]; const float* bv = (const float*)d_in[7];
    const float* Wo = (const float*)d_in[8]; const float* bo = (const float*)d_in[9];

    float* out = (float*)d_out;
    u16*   ws  = (u16*)d_ws;

    // bf16 K+V per bh = 1 MiB; adaptive chunk (ws certified >= 16 MiB).
    const size_t per_bh = (size_t)2 * L_ * 64 * 2;
    int chunk = 16;
    while (chunk > 1 && (size_t)chunk * per_bh > ws_size) chunk >>= 1;

    u16* Kws = ws;
    u16* Vws = Kws + (size_t)chunk * (L_ * 64);

    for (int bh0 = 0; bh0 < BH_; bh0 += chunk) {
        kvproj_kernel<<<dim3(chunk, L_ / 64, 2), 256, 0, stream>>>(
            x, Wk, bk, Wv, bv, Kws, Vws, bh0);
        attn_kernel<<<dim3(L_ / 128, chunk), 512, 0, stream>>>(
            x, Wq, bq, Kws, Vws, mask, out, bh0);
    }
    outproj_kernel<<<dim3(M_ / 32), 256, 0, stream>>>(out, Wo, bo);
}

// Round 2
// 340.728 us; speedup vs baseline: 1.2090x; 1.2090x over previous
//
#include <hip/hip_runtime.h>

// Round 17: swapped-QK^T lane-local softmax (T12 pattern).
// mfma(kf, qf) puts S^T[key][q] in regs: one q-row per lane (q = lane&15),
// 16 keys/lane. Row max/sum = 15 in-reg ops + 2 shfl_xor (was 32 shfl).
// Mask folded into MFMA C-init as additive -10000 bias (exact after fp32
// exp underflow). P packed with v_cvt_pk_bf16_f32 (8 ops, was ~56 f2b ops)
// and written as 4x ds_write_b64 (was 16x ds_write_b16). alpha/l are scalar
// per lane; oacc rescale gets alpha per C-row via a 64B per-wave LDS bounce.
// kvproj/outproj unchanged.

#define B_  2
#define L_  4096
#define D_  512
#define H_  8
#define BH_ 16
#define M_  8192

typedef __attribute__((ext_vector_type(8))) short short8;    // 8 bf16 = 4 VGPR
typedef __attribute__((ext_vector_type(4))) float f32x4;
typedef unsigned short u16;

static __device__ __forceinline__ u16 f2b(float f) {
    union { float f; unsigned i; } x; x.f = f;
    unsigned r = x.i + 0x7fff + ((x.i >> 16) & 1);   // RNE
    return (u16)(r >> 16);
}

// Pack 2 fp32 -> 2 bf16 (RNE) in one instruction.
static __device__ __forceinline__ unsigned cvt_pk_bf16(float lo, float hi) {
    unsigned r;
    asm("v_cvt_pk_bf16_f32 %0, %1, %2" : "=v"(r) : "v"(lo), "v"(hi));
    return r;
}

// Stage 8 consecutive fp32 -> 8 bf16 (16 B) into LDS.
static __device__ __forceinline__ void stage8f(u16* dst, const float* s) {
    const float4 a = *(const float4*)s;
    const float4 b = *(const float4*)(s + 4);
    u16 tmp[8] = { f2b(a.x), f2b(a.y), f2b(a.z), f2b(a.w),
                   f2b(b.x), f2b(b.y), f2b(b.z), f2b(b.w) };
    *(uint4*)dst = *(const uint4*)tmp;
}

// ---------------------------------------------------------------------------
// K/V projection. grid (chunk, L/64, 2) z=0->K (row-major L x 64),
// z=1->V (TRANSPOSED: 64 dims x L keys). Block 64x64 tile, 4 waves 2x2.
// ---------------------------------------------------------------------------
__global__ __launch_bounds__(256) void kvproj_kernel(
    const float* __restrict__ x,
    const float* __restrict__ Wk, const float* __restrict__ bk,
    const float* __restrict__ Wv, const float* __restrict__ bv,
    u16* __restrict__ Kws, u16* __restrict__ Vws, int bh0)
{
    __shared__ __align__(16) unsigned char sm[10240];
    u16 (*As)[40] = (u16(*)[40])sm;            // 5120 B
    u16 (*Bs)[40] = (u16(*)[40])(sm + 5120);   // 5120 B
    u16 (*Ts)[73] = (u16(*)[73])sm;            // 9344 B (V transpose bounce)

    const int t    = threadIdx.x;
    const int wid  = t >> 6, lane = t & 63;
    const int m15  = lane & 15, quad = lane >> 4;
    const int wm   = wid >> 1, wn = wid & 1;

    const int bh = bh0 + blockIdx.x;
    const int b  = bh >> 3, h = bh & 7;
    const int l0 = blockIdx.y * 64;
    const float* W  = blockIdx.z ? Wv : Wk;
    const float* bi = blockIdx.z ? bv : bk;

    const int lrow = t >> 2;        // 0..63
    const int lcol = (t & 3) * 8;   // 0,8,16,24
    const size_t xrow0 = (size_t)b * L_ + l0;

    f32x4 acc[2][2] = {};

    for (int k0 = 0; k0 < 512; k0 += 32) {
        __syncthreads();
        stage8f(&As[lrow][lcol], x + (xrow0 + lrow) * 512 + k0 + lcol);
        stage8f(&Bs[lrow][lcol], W + (size_t)(h * 64 + lrow) * 512 + k0 + lcol);
        __syncthreads();

        short8 afr[2], bfr[2];
#pragma unroll
        for (int mi = 0; mi < 2; ++mi)
            afr[mi] = *(const short8*)(&As[wm * 32 + mi * 16 + m15][quad * 8]);
#pragma unroll
        for (int ni = 0; ni < 2; ++ni)
            bfr[ni] = *(const short8*)(&Bs[wn * 32 + ni * 16 + m15][quad * 8]);
#pragma unroll
        for (int mi = 0; mi < 2; ++mi)
#pragma unroll
            for (int ni = 0; ni < 2; ++ni)
                acc[mi][ni] = __builtin_amdgcn_mfma_f32_16x16x32_bf16(
                    afr[mi], bfr[ni], acc[mi][ni], 0, 0, 0);
    }

    if (blockIdx.z == 0) {
        u16* out = Kws + (size_t)blockIdx.x * (L_ * 64);
#pragma unroll
        for (int mi = 0; mi < 2; ++mi)
#pragma unroll
            for (int ni = 0; ni < 2; ++ni) {
                const int d  = wn * 32 + ni * 16 + m15;
                const float bv_ = bi[h * 64 + d];
#pragma unroll
                for (int r = 0; r < 4; ++r) {
                    const int l = l0 + wm * 32 + mi * 16 + quad * 4 + r;
                    out[(size_t)l * 64 + d] = f2b(acc[mi][ni][r] + bv_);
                }
            }
    } else {
        __syncthreads();   // all MFMA LDS reads done before overwrite
#pragma unroll
        for (int mi = 0; mi < 2; ++mi)
#pragma unroll
            for (int ni = 0; ni < 2; ++ni) {
                const int d  = wn * 32 + ni * 16 + m15;
                const float bv_ = bi[h * 64 + d];
#pragma unroll
                for (int r = 0; r < 4; ++r)
                    Ts[wm * 32 + mi * 16 + quad * 4 + r][d] = f2b(acc[mi][ni][r] + bv_);
            }
        __syncthreads();
        u16* Vt = Vws + (size_t)blockIdx.x * ((size_t)64 * L_);
        const int d  = t >> 2;
        const int ls = (t & 3) * 16;
        u16 pk[16];
#pragma unroll
        for (int j = 0; j < 16; ++j) pk[j] = Ts[ls + j][d];
        u16* dst = Vt + (size_t)d * L_ + l0 + ls;
        *(uint4*)dst       = *(const uint4*)pk;
        *(uint4*)(dst + 8) = *(const uint4*)(pk + 8);
    }
}

// ---------------------------------------------------------------------------
// Fused Q-projection + flash attention. grid (L/128, chunk), block 512.
// 8 waves; wave w owns q-rows [16w, 16w+16). Register-prefetched k-loop.
// LDS phased union: ph1 {xs[128][40], wqs[64][40]} overlays ph2 {Ks, Vts}.
// Per-wave region: P[16][72] u16 (2304 B) + 64 B alpha/l bounce = 2368 B.
// ---------------------------------------------------------------------------
#define KS_OFF  0
#define VTS_OFF 9216
#define PS_OFF  18432
#define PW_PITCH 2368
#define MS_OFF  (PS_OFF + 8 * PW_PITCH)   // 37376
__global__ __launch_bounds__(512) void attn_kernel(
    const float* __restrict__ x,
    const float* __restrict__ Wq, const float* __restrict__ bq,
    const u16* __restrict__ Kws, const u16* __restrict__ Vws,
    const int* __restrict__ mask,
    float* __restrict__ O, int bh0)
{
    __shared__ __align__(16) unsigned char sm[MS_OFF + 256];
    u16 (*xs)[40]  = (u16(*)[40])sm;                    // ph1, 10240 B
    u16 (*wqs)[40] = (u16(*)[40])(sm + 10240);          // ph1, 5120 B
    u16 (*Ks)[72]  = (u16(*)[72])(sm + KS_OFF);         // ph2, 9216 B [key][dim]
    u16 (*Vts)[72] = (u16(*)[72])(sm + VTS_OFF);        // ph2, 9216 B [dim][key]
    float* Msb     = (float*)(sm + MS_OFF);             // additive bias: 0 / -1e4

    const int t    = threadIdx.x;
    const int wid  = t >> 6, lane = t & 63;
    const int m15  = lane & 15, quad = lane >> 4;
    u16 (*Psw)[72] = (u16(*)[72])(sm + PS_OFF + wid * PW_PITCH);   // per-wave P
    float* Alf     = (float*)(sm + PS_OFF + wid * PW_PITCH + 2304); // 16 f32

    const int bh = bh0 + blockIdx.y;
    const int b  = bh >> 3, h = bh & 7;
    const int q0 = blockIdx.x * 128;
    const u16* Kc  = Kws + (size_t)blockIdx.y * (L_ * 64);
    const u16* Vtc = Vws + (size_t)blockIdx.y * ((size_t)64 * L_);

    // ---- phase 1: Q[128][64] = x[q-tile] @ Wq[h]^T + bq, pre-scaled 1/8 ----
    f32x4 qacc[4] = {};
    {
        const int xr = t >> 2, xc = (t & 3) * 8;         // 128 rows x 4 groups
        for (int k0 = 0; k0 < 512; k0 += 32) {
            __syncthreads();
            stage8f(&xs[xr][xc], x + ((size_t)b * L_ + q0 + xr) * 512 + k0 + xc);
            if (t < 256)
                stage8f(&wqs[xr][xc], Wq + (size_t)(h * 64 + xr) * 512 + k0 + xc);
            __syncthreads();
            const short8 afr = *(const short8*)(&xs[wid * 16 + m15][quad * 8]);
#pragma unroll
            for (int ni = 0; ni < 4; ++ni) {
                const short8 bfr = *(const short8*)(&wqs[ni * 16 + m15][quad * 8]);
                qacc[ni] = __builtin_amdgcn_mfma_f32_16x16x32_bf16(afr, bfr, qacc[ni], 0, 0, 0);
            }
        }
    }
    // C-layout -> per-wave Ps slice -> B-frag for swapped QK (wave-local, DS in-order)
    short8 qf[2];
#pragma unroll
    for (int ni = 0; ni < 4; ++ni) {
        const float bv_ = bq[h * 64 + ni * 16 + m15];
#pragma unroll
        for (int r = 0; r < 4; ++r)
            Psw[quad * 4 + r][ni * 16 + m15] = f2b((qacc[ni][r] + bv_) * 0.125f);
    }
#pragma unroll
    for (int kc = 0; kc < 2; ++kc)
        qf[kc] = *(const short8*)(&Psw[m15][kc * 32 + quad * 8]);

    // ---- flash loop over 64-key tiles, register-prefetched ----
    const int srow = t >> 3;            // 0..63
    const int scol = (t & 7) * 8;       // 0..56
    uint4 kreg = *(const uint4*)(Kc  + (size_t)srow * 64 + scol);
    uint4 vreg = *(const uint4*)(Vtc + (size_t)srow * L_ + scol);
    int   mreg = (t < 64) ? mask[b * L_ + t] : 0;

    float m_i = -1e30f, l_i = 0.0f;     // per lane: q-row = m15
    f32x4 oacc[4] = {};

    for (int kt = 0; kt < 64; ++kt) {
        __syncthreads();                 // prior tile's LDS reads done
        *(uint4*)(&Ks [srow][scol]) = kreg;
        *(uint4*)(&Vts[srow][scol]) = vreg;
        if (t < 64) Msb[t] = (mreg == 0) ? -10000.0f : 0.0f;
        __syncthreads();                 // tile kt visible
        if (kt + 1 < 64) {               // prefetch kt+1 (overlaps compute)
            const int k1 = (kt + 1) * 64;
            kreg = *(const uint4*)(Kc  + (size_t)(k1 + srow) * 64 + scol);
            vreg = *(const uint4*)(Vtc + (size_t)srow * L_ + k1 + scol);
            if (t < 64) mreg = mask[b * L_ + k1 + t];
        }

        // S^T = K (Q/8)^T with mask bias in C-init.
        // Lane holds S^T[key = ni*16 + quad*4 + r][q = m15].
        f32x4 s[4];
#pragma unroll
        for (int ni = 0; ni < 4; ++ni) {
            f32x4 sa = *(const f32x4*)(&Msb[ni * 16 + quad * 4]);
#pragma unroll
            for (int kc = 0; kc < 2; ++kc) {
                const short8 kf = *(const short8*)(&Ks[ni * 16 + m15][kc * 32 + quad * 8]);
                sa = __builtin_amdgcn_mfma_f32_16x16x32_bf16(kf, qf[kc], sa, 0, 0, 0);
            }
            s[ni] = sa;
        }

        // q-row max: 15 in-reg fmax + 2-step butterfly across quads
        float mx = fmaxf(
            fmaxf(fmaxf(fmaxf(s[0][0], s[0][1]), fmaxf(s[0][2], s[0][3])),
                  fmaxf(fmaxf(s[1][0], s[1][1]), fmaxf(s[1][2], s[1][3]))),
            fmaxf(fmaxf(fmaxf(s[2][0], s[2][1]), fmaxf(s[2][2], s[2][3])),
                  fmaxf(fmaxf(s[3][0], s[3][1]), fmaxf(s[3][2], s[3][3]))));
        mx = fmaxf(mx, __shfl_xor(mx, 16));
        mx = fmaxf(mx, __shfl_xor(mx, 32));

        // exact defer-rescale: alpha == 1 when no lane's max grew
        if (__any(mx > m_i)) {
            const float mnew = fmaxf(m_i, mx);
            const float a = __expf(m_i - mnew);
            m_i = mnew;
            l_i *= a;
            if (quad == 0) Alf[m15] = a;             // per-wave, DS in-order
            const f32x4 a4 = *(const f32x4*)(&Alf[quad * 4]);
#pragma unroll
            for (int ni = 0; ni < 4; ++ni)
#pragma unroll
                for (int r = 0; r < 4; ++r)
                    oacc[ni][r] *= a4[r];
        }

        // P = exp(S - m): in-reg; pack via cvt_pk; 4x ds_write_b64
        float ss = 0.0f;
#pragma unroll
        for (int ni = 0; ni < 4; ++ni) {
            const float p0 = __expf(s[ni][0] - m_i);
            const float p1 = __expf(s[ni][1] - m_i);
            const float p2 = __expf(s[ni][2] - m_i);
            const float p3 = __expf(s[ni][3] - m_i);
            ss += (p0 + p1) + (p2 + p3);
            uint2 w;
            w.x = cvt_pk_bf16(p0, p1);
            w.y = cvt_pk_bf16(p2, p3);
            *(uint2*)(&Psw[m15][ni * 16 + quad * 4]) = w;
        }
        ss += __shfl_xor(ss, 16);
        ss += __shfl_xor(ss, 32);
        l_i += ss;

        short8 pf[2];
#pragma unroll
        for (int kc = 0; kc < 2; ++kc)
            pf[kc] = *(const short8*)(&Psw[m15][kc * 32 + quad * 8]);

        // O += P V
#pragma unroll
        for (int ni = 0; ni < 4; ++ni) {
#pragma unroll
            for (int kc = 0; kc < 2; ++kc) {
                const short8 vf = *(const short8*)(&Vts[ni * 16 + m15][kc * 32 + quad * 8]);
                oacc[ni] = __builtin_amdgcn_mfma_f32_16x16x32_bf16(pf[kc], vf, oacc[ni], 0, 0, 0);
            }
        }
    }

    // epilogue: O /= l -> fp32 (B, L, 512). l per C-row via per-wave bounce.
    if (quad == 0) Alf[m15] = l_i;
    const f32x4 l4 = *(const f32x4*)(&Alf[quad * 4]);
#pragma unroll
    for (int ni = 0; ni < 4; ++ni)
#pragma unroll
        for (int r = 0; r < 4; ++r) {
            const int qrow = q0 + wid * 16 + quad * 4 + r;
            O[((size_t)b * L_ + qrow) * 512 + h * 64 + ni * 16 + m15] =
                oacc[ni][r] / l4[r];
        }
}

// ---------------------------------------------------------------------------
// In-place fp32 output projection: AO = AO @ Wo^T + bo, (M,512).
// ---------------------------------------------------------------------------
__global__ __launch_bounds__(256) void outproj_kernel(
    float* __restrict__ AO,
    const float* __restrict__ Wo, const float* __restrict__ bo)
{
    __shared__ __align__(16) u16 As[32][520];
    __shared__ __align__(16) u16 Ws_[64][40];

    const int t    = threadIdx.x;
    const int wid  = t >> 6, lane = t & 63;
    const int m15  = lane & 15, quad = lane >> 4;
    const int wm   = wid >> 1, wn = wid & 1;
    const int bm   = blockIdx.x * 32;

#pragma unroll
    for (int it = 0; it < 8; ++it) {
        const int idx = t + it * 256;            // 0..2047
        const int row = idx >> 6, c8 = (idx & 63) * 8;
        stage8f(&As[row][c8], AO + (size_t)(bm + row) * 512 + c8);
    }
    const int lrow = t >> 2;
    const int lcol = (t & 3) * 8;
    __syncthreads();

    for (int n0 = 0; n0 < 512; n0 += 64) {
        f32x4 acc[2] = {};
        for (int k0 = 0; k0 < 512; k0 += 32) {
            __syncthreads();
            stage8f(&Ws_[lrow][lcol], Wo + (size_t)(n0 + lrow) * 512 + k0 + lcol);
            __syncthreads();
            const short8 afr = *(const short8*)(&As[wm * 16 + m15][k0 + quad * 8]);
#pragma unroll
            for (int ni = 0; ni < 2; ++ni) {
                const short8 bfr = *(const short8*)(&Ws_[wn * 32 + ni * 16 + m15][quad * 8]);
                acc[ni] = __builtin_amdgcn_mfma_f32_16x16x32_bf16(afr, bfr, acc[ni], 0, 0, 0);
            }
        }
#pragma unroll
        for (int ni = 0; ni < 2; ++ni) {
            const int col = n0 + wn * 32 + ni * 16 + m15;
            const float bv_ = bo[col];
#pragma unroll
            for (int r = 0; r < 4; ++r) {
                const int row = bm + wm * 16 + quad * 4 + r;
                AO[(size_t)row * 512 + col] = acc[ni][r] + bv_;
            }
        }
    }
}

extern "C" void kernel_launch(void* const* d_in, const int* in_sizes, int n_in,
                              void* d_out, int out_size, void* d_ws, size_t ws_size,
                              hipStream_t stream) {
    const float* x    = (const float*)d_in[0];
    const int*   mask = (const int*)d_in[1];
    const float* Wq = (const float*)d_in[2]; const float* bq = (const float*)d_in[3];
    const float* Wk = (const float*)d_in[4]; const float* bk = (const float*)d_in[5];
    const float* Wv = (const float*)d_in[6]; const float* bv = (const float*)d_in[7];
    const float* Wo = (const float*)d_in[8]; const float* bo = (const float*)d_in[9];

    float* out = (float*)d_out;
    u16*   ws  = (u16*)d_ws;

    // bf16 K+V per bh = 1 MiB; adaptive chunk (ws certified >= 16 MiB).
    const size_t per_bh = (size_t)2 * L_ * 64 * 2;
    int chunk = 16;
    while (chunk > 1 && (size_t)chunk * per_bh > ws_size) chunk >>= 1;

    u16* Kws = ws;
    u16* Vws = Kws + (size_t)chunk * (L_ * 64);

    for (int bh0 = 0; bh0 < BH_; bh0 += chunk) {
        kvproj_kernel<<<dim3(chunk, L_ / 64, 2), 256, 0, stream>>>(
            x, Wk, bk, Wv, bv, Kws, Vws, bh0);
        attn_kernel<<<dim3(L_ / 128, chunk), 512, 0, stream>>>(
            x, Wq, bq, Kws, Vws, mask, out, bh0);
    }
    outproj_kernel<<<dim3(M_ / 32), 256, 0, stream>>>(out, Wo, bo);
}

// Round 3
// 271.534 us; speedup vs baseline: 1.5171x; 1.2548x over previous
//
#include <hip/hip_runtime.h>

// Round 18: kill the projection-GEMM overhead.
// (1) fp32->bf16 staging via v_cvt_pk_bf16_f32 (4 ops/8 vals, was ~40 with
//     the f2b bit-trick) in kvproj, attn phase-1, outproj.
// (2) Register-prefetch global loads across the barrier in kvproj, attn
//     phase-1, outproj (loads overlap compute instead of serializing).
// (3) outproj v2: attn writes AO as bf16 into ws (+8 MiB past K/V, runtime
//     size check), outproj N-splits to (128,8)=1024 blocks (was 256 = 1
//     block/CU), reads bf16 A with no conversion, writes fp32 d_out.
//     Fallback (ws < 24 MiB): old in-place path.
// (4) attn: log2-domain softmax (fold log2e into Q scale + mask bias,
//     exp2 directly) - saves 16 v_mul per tile.

#define B_  2
#define L_  4096
#define D_  512
#define H_  8
#define BH_ 16
#define M_  8192

typedef __attribute__((ext_vector_type(8))) short short8;    // 8 bf16 = 4 VGPR
typedef __attribute__((ext_vector_type(4))) float f32x4;
typedef unsigned short u16;

#if __has_builtin(__builtin_amdgcn_exp2f)
#define EX2(x) __builtin_amdgcn_exp2f(x)
#else
#define EX2(x) exp2f(x)
#endif

static __device__ __forceinline__ u16 f2b(float f) {
    union { float f; unsigned i; } x; x.f = f;
    unsigned r = x.i + 0x7fff + ((x.i >> 16) & 1);   // RNE
    return (u16)(r >> 16);
}

// Pack 2 fp32 -> 2 bf16 (RNE, lo = src0) in one instruction.
static __device__ __forceinline__ unsigned cvt_pk_bf16(float lo, float hi) {
    unsigned r;
    asm("v_cvt_pk_bf16_f32 %0, %1, %2" : "=v"(r) : "v"(lo), "v"(hi));
    return r;
}

// 8 fp32 (two float4) -> 8 bf16 packed in a uint4.
static __device__ __forceinline__ uint4 pk8(const float4& a, const float4& b) {
    uint4 o;
    o.x = cvt_pk_bf16(a.x, a.y);
    o.y = cvt_pk_bf16(a.z, a.w);
    o.z = cvt_pk_bf16(b.x, b.y);
    o.w = cvt_pk_bf16(b.z, b.w);
    return o;
}

static __device__ __forceinline__ void stage8f(u16* dst, const float* s) {
    const float4 a = *(const float4*)s;
    const float4 b = *(const float4*)(s + 4);
    *(uint4*)dst = pk8(a, b);
}

// ---------------------------------------------------------------------------
// K/V projection. grid (chunk, L/64, 2) z=0->K (row-major L x 64),
// z=1->V (TRANSPOSED: 64 dims x L keys). Block 64x64 tile, 4 waves 2x2.
// Register-prefetched K-loop, cvt_pk staging.
// ---------------------------------------------------------------------------
__global__ __launch_bounds__(256) void kvproj_kernel(
    const float* __restrict__ x,
    const float* __restrict__ Wk, const float* __restrict__ bk,
    const float* __restrict__ Wv, const float* __restrict__ bv,
    u16* __restrict__ Kws, u16* __restrict__ Vws, int bh0)
{
    __shared__ __align__(16) unsigned char sm[10240];
    u16 (*As)[40] = (u16(*)[40])sm;            // 5120 B
    u16 (*Bs)[40] = (u16(*)[40])(sm + 5120);   // 5120 B
    u16 (*Ts)[73] = (u16(*)[73])sm;            // 9344 B (V transpose bounce)

    const int t    = threadIdx.x;
    const int wid  = t >> 6, lane = t & 63;
    const int m15  = lane & 15, quad = lane >> 4;
    const int wm   = wid >> 1, wn = wid & 1;

    const int bh = bh0 + blockIdx.x;
    const int b  = bh >> 3, h = bh & 7;
    const int l0 = blockIdx.y * 64;
    const float* W  = blockIdx.z ? Wv : Wk;
    const float* bi = blockIdx.z ? bv : bk;

    const int lrow = t >> 2;        // 0..63
    const int lcol = (t & 3) * 8;   // 0,8,16,24
    const size_t xrow0 = (size_t)b * L_ + l0;

    const float* Ap = x + (xrow0 + lrow) * 512 + lcol;
    const float* Bp = W + (size_t)(h * 64 + lrow) * 512 + lcol;
    float4 a0 = *(const float4*)(Ap), a1 = *(const float4*)(Ap + 4);
    float4 b0 = *(const float4*)(Bp), b1 = *(const float4*)(Bp + 4);

    f32x4 acc[2][2] = {};

    for (int k0 = 0; k0 < 512; k0 += 32) {
        __syncthreads();
        *(uint4*)(&As[lrow][lcol]) = pk8(a0, a1);
        *(uint4*)(&Bs[lrow][lcol]) = pk8(b0, b1);
        __syncthreads();
        if (k0 + 32 < 512) {            // prefetch next K-chunk (hides latency)
            a0 = *(const float4*)(Ap + k0 + 32); a1 = *(const float4*)(Ap + k0 + 36);
            b0 = *(const float4*)(Bp + k0 + 32); b1 = *(const float4*)(Bp + k0 + 36);
        }

        short8 afr[2], bfr[2];
#pragma unroll
        for (int mi = 0; mi < 2; ++mi)
            afr[mi] = *(const short8*)(&As[wm * 32 + mi * 16 + m15][quad * 8]);
#pragma unroll
        for (int ni = 0; ni < 2; ++ni)
            bfr[ni] = *(const short8*)(&Bs[wn * 32 + ni * 16 + m15][quad * 8]);
#pragma unroll
        for (int mi = 0; mi < 2; ++mi)
#pragma unroll
            for (int ni = 0; ni < 2; ++ni)
                acc[mi][ni] = __builtin_amdgcn_mfma_f32_16x16x32_bf16(
                    afr[mi], bfr[ni], acc[mi][ni], 0, 0, 0);
    }

    if (blockIdx.z == 0) {
        u16* out = Kws + (size_t)blockIdx.x * (L_ * 64);
#pragma unroll
        for (int mi = 0; mi < 2; ++mi)
#pragma unroll
            for (int ni = 0; ni < 2; ++ni) {
                const int d  = wn * 32 + ni * 16 + m15;
                const float bv_ = bi[h * 64 + d];
#pragma unroll
                for (int r = 0; r < 4; ++r) {
                    const int l = l0 + wm * 32 + mi * 16 + quad * 4 + r;
                    out[(size_t)l * 64 + d] = f2b(acc[mi][ni][r] + bv_);
                }
            }
    } else {
        __syncthreads();   // all MFMA LDS reads done before overwrite
#pragma unroll
        for (int mi = 0; mi < 2; ++mi)
#pragma unroll
            for (int ni = 0; ni < 2; ++ni) {
                const int d  = wn * 32 + ni * 16 + m15;
                const float bv_ = bi[h * 64 + d];
#pragma unroll
                for (int r = 0; r < 4; ++r)
                    Ts[wm * 32 + mi * 16 + quad * 4 + r][d] = f2b(acc[mi][ni][r] + bv_);
            }
        __syncthreads();
        u16* Vt = Vws + (size_t)blockIdx.x * ((size_t)64 * L_);
        const int d  = t >> 2;
        const int ls = (t & 3) * 16;
        u16 pk[16];
#pragma unroll
        for (int j = 0; j < 16; ++j) pk[j] = Ts[ls + j][d];
        u16* dst = Vt + (size_t)d * L_ + l0 + ls;
        *(uint4*)dst       = *(const uint4*)pk;
        *(uint4*)(dst + 8) = *(const uint4*)(pk + 8);
    }
}

// ---------------------------------------------------------------------------
// Fused Q-projection + flash attention. grid (L/128, chunk), block 512.
// 8 waves; wave w owns q-rows [16w, 16w+16). Swapped-QK^T lane-local softmax
// in log2 domain. Writes bf16 AO to Obf if non-null, else fp32 to O.
// ---------------------------------------------------------------------------
#define KS_OFF  0
#define VTS_OFF 9216
#define PS_OFF  18432
#define PW_PITCH 2368
#define MS_OFF  (PS_OFF + 8 * PW_PITCH)   // 37376
__global__ __launch_bounds__(512) void attn_kernel(
    const float* __restrict__ x,
    const float* __restrict__ Wq, const float* __restrict__ bq,
    const u16* __restrict__ Kws, const u16* __restrict__ Vws,
    const int* __restrict__ mask,
    float* __restrict__ O, u16* __restrict__ Obf, int bh0)
{
    __shared__ __align__(16) unsigned char sm[MS_OFF + 256];
    u16 (*xs)[40]  = (u16(*)[40])sm;                    // ph1, 10240 B
    u16 (*wqs)[40] = (u16(*)[40])(sm + 10240);          // ph1, 5120 B
    u16 (*Ks)[72]  = (u16(*)[72])(sm + KS_OFF);         // ph2, 9216 B [key][dim]
    u16 (*Vts)[72] = (u16(*)[72])(sm + VTS_OFF);        // ph2, 9216 B [dim][key]
    float* Msb     = (float*)(sm + MS_OFF);             // additive bias (log2): 0 / -14427

    const int t    = threadIdx.x;
    const int wid  = t >> 6, lane = t & 63;
    const int m15  = lane & 15, quad = lane >> 4;
    u16 (*Psw)[72] = (u16(*)[72])(sm + PS_OFF + wid * PW_PITCH);   // per-wave P
    float* Alf     = (float*)(sm + PS_OFF + wid * PW_PITCH + 2304); // 16 f32

    const int bh = bh0 + blockIdx.y;
    const int b  = bh >> 3, h = bh & 7;
    const int q0 = blockIdx.x * 128;
    const u16* Kc  = Kws + (size_t)blockIdx.y * (L_ * 64);
    const u16* Vtc = Vws + (size_t)blockIdx.y * ((size_t)64 * L_);

    // ---- phase 1: Q[128][64] = x[q-tile] @ Wq[h]^T + bq, scaled log2e/8 ----
    f32x4 qacc[4] = {};
    {
        const int xr = t >> 2, xc = (t & 3) * 8;         // 128 rows x 4 groups
        const float* xp = x + ((size_t)b * L_ + q0 + xr) * 512 + xc;
        const float* wp = Wq + (size_t)(h * 64 + xr) * 512 + xc;
        float4 xa0 = *(const float4*)xp, xa1 = *(const float4*)(xp + 4);
        float4 wa0 = {}, wa1 = {};
        if (t < 256) { wa0 = *(const float4*)wp; wa1 = *(const float4*)(wp + 4); }
        for (int k0 = 0; k0 < 512; k0 += 32) {
            __syncthreads();
            *(uint4*)(&xs[xr][xc]) = pk8(xa0, xa1);
            if (t < 256) *(uint4*)(&wqs[xr][xc]) = pk8(wa0, wa1);
            __syncthreads();
            if (k0 + 32 < 512) {
                xa0 = *(const float4*)(xp + k0 + 32); xa1 = *(const float4*)(xp + k0 + 36);
                if (t < 256) {
                    wa0 = *(const float4*)(wp + k0 + 32); wa1 = *(const float4*)(wp + k0 + 36);
                }
            }
            const short8 afr = *(const short8*)(&xs[wid * 16 + m15][quad * 8]);
#pragma unroll
            for (int ni = 0; ni < 4; ++ni) {
                const short8 bfr = *(const short8*)(&wqs[ni * 16 + m15][quad * 8]);
                qacc[ni] = __builtin_amdgcn_mfma_f32_16x16x32_bf16(afr, bfr, qacc[ni], 0, 0, 0);
            }
        }
    }
    // C-layout -> per-wave Ps slice -> B-frag for swapped QK (wave-local, DS in-order)
    const float QSCALE = 0.125f * 1.44269504089f;   // /sqrt(dk) * log2(e)
    short8 qf[2];
#pragma unroll
    for (int ni = 0; ni < 4; ++ni) {
        const float bv_ = bq[h * 64 + ni * 16 + m15];
#pragma unroll
        for (int r = 0; r < 4; ++r)
            Psw[quad * 4 + r][ni * 16 + m15] = f2b((qacc[ni][r] + bv_) * QSCALE);
    }
#pragma unroll
    for (int kc = 0; kc < 2; ++kc)
        qf[kc] = *(const short8*)(&Psw[m15][kc * 32 + quad * 8]);

    // ---- flash loop over 64-key tiles, register-prefetched ----
    const int srow = t >> 3;            // 0..63
    const int scol = (t & 7) * 8;       // 0..56
    uint4 kreg = *(const uint4*)(Kc  + (size_t)srow * 64 + scol);
    uint4 vreg = *(const uint4*)(Vtc + (size_t)srow * L_ + scol);
    int   mreg = (t < 64) ? mask[b * L_ + t] : 0;

    float m_i = -1e30f, l_i = 0.0f;     // per lane: q-row = m15 (log2 domain)
    f32x4 oacc[4] = {};

    for (int kt = 0; kt < 64; ++kt) {
        __syncthreads();                 // prior tile's LDS reads done
        *(uint4*)(&Ks [srow][scol]) = kreg;
        *(uint4*)(&Vts[srow][scol]) = vreg;
        if (t < 64) Msb[t] = (mreg == 0) ? -14427.0f : 0.0f;
        __syncthreads();                 // tile kt visible
        if (kt + 1 < 64) {               // prefetch kt+1 (overlaps compute)
            const int k1 = (kt + 1) * 64;
            kreg = *(const uint4*)(Kc  + (size_t)(k1 + srow) * 64 + scol);
            vreg = *(const uint4*)(Vtc + (size_t)srow * L_ + k1 + scol);
            if (t < 64) mreg = mask[b * L_ + k1 + t];
        }

        // S^T (log2-scaled) = K (Q*log2e/8)^T with mask bias in C-init.
        // Lane holds S^T[key = ni*16 + quad*4 + r][q = m15].
        f32x4 s[4];
#pragma unroll
        for (int ni = 0; ni < 4; ++ni) {
            f32x4 sa = *(const f32x4*)(&Msb[ni * 16 + quad * 4]);
#pragma unroll
            for (int kc = 0; kc < 2; ++kc) {
                const short8 kf = *(const short8*)(&Ks[ni * 16 + m15][kc * 32 + quad * 8]);
                sa = __builtin_amdgcn_mfma_f32_16x16x32_bf16(kf, qf[kc], sa, 0, 0, 0);
            }
            s[ni] = sa;
        }

        // q-row max: 15 in-reg fmax + 2-step butterfly across quads
        float mx = fmaxf(
            fmaxf(fmaxf(fmaxf(s[0][0], s[0][1]), fmaxf(s[0][2], s[0][3])),
                  fmaxf(fmaxf(s[1][0], s[1][1]), fmaxf(s[1][2], s[1][3]))),
            fmaxf(fmaxf(fmaxf(s[2][0], s[2][1]), fmaxf(s[2][2], s[2][3])),
                  fmaxf(fmaxf(s[3][0], s[3][1]), fmaxf(s[3][2], s[3][3]))));
        mx = fmaxf(mx, __shfl_xor(mx, 16));
        mx = fmaxf(mx, __shfl_xor(mx, 32));

        // exact defer-rescale: alpha == 1 when no lane's max grew
        if (__any(mx > m_i)) {
            const float mnew = fmaxf(m_i, mx);
            const float a = EX2(m_i - mnew);
            m_i = mnew;
            l_i *= a;
            if (quad == 0) Alf[m15] = a;             // per-wave, DS in-order
            const f32x4 a4 = *(const f32x4*)(&Alf[quad * 4]);
#pragma unroll
            for (int ni = 0; ni < 4; ++ni)
#pragma unroll
                for (int r = 0; r < 4; ++r)
                    oacc[ni][r] *= a4[r];
        }

        // P = exp2(S - m): in-reg; pack via cvt_pk; 4x ds_write_b64
        float ss = 0.0f;
#pragma unroll
        for (int ni = 0; ni < 4; ++ni) {
            const float p0 = EX2(s[ni][0] - m_i);
            const float p1 = EX2(s[ni][1] - m_i);
            const float p2 = EX2(s[ni][2] - m_i);
            const float p3 = EX2(s[ni][3] - m_i);
            ss += (p0 + p1) + (p2 + p3);
            uint2 w;
            w.x = cvt_pk_bf16(p0, p1);
            w.y = cvt_pk_bf16(p2, p3);
            *(uint2*)(&Psw[m15][ni * 16 + quad * 4]) = w;
        }
        ss += __shfl_xor(ss, 16);
        ss += __shfl_xor(ss, 32);
        l_i += ss;

        short8 pf[2];
#pragma unroll
        for (int kc = 0; kc < 2; ++kc)
            pf[kc] = *(const short8*)(&Psw[m15][kc * 32 + quad * 8]);

        // O += P V
#pragma unroll
        for (int ni = 0; ni < 4; ++ni) {
#pragma unroll
            for (int kc = 0; kc < 2; ++kc) {
                const short8 vf = *(const short8*)(&Vts[ni * 16 + m15][kc * 32 + quad * 8]);
                oacc[ni] = __builtin_amdgcn_mfma_f32_16x16x32_bf16(pf[kc], vf, oacc[ni], 0, 0, 0);
            }
        }
    }

    // epilogue: O /= l. l per C-row via per-wave bounce.
    if (quad == 0) Alf[m15] = l_i;
    const f32x4 l4 = *(const f32x4*)(&Alf[quad * 4]);
    if (Obf) {
#pragma unroll
        for (int ni = 0; ni < 4; ++ni)
#pragma unroll
            for (int r = 0; r < 4; ++r) {
                const int qrow = q0 + wid * 16 + quad * 4 + r;
                Obf[((size_t)b * L_ + qrow) * 512 + h * 64 + ni * 16 + m15] =
                    f2b(oacc[ni][r] / l4[r]);
            }
    } else {
#pragma unroll
        for (int ni = 0; ni < 4; ++ni)
#pragma unroll
            for (int r = 0; r < 4; ++r) {
                const int qrow = q0 + wid * 16 + quad * 4 + r;
                O[((size_t)b * L_ + qrow) * 512 + h * 64 + ni * 16 + m15] =
                    oacc[ni][r] / l4[r];
            }
    }
}

// ---------------------------------------------------------------------------
// Output projection v2: out = AO(bf16) @ Wo^T + bo, (M,512) fp32.
// grid (M/64, 512/64) = (128, 8) -> 4 blocks/CU. Block 64x64 tile, 4 waves.
// A is already bf16 (no conversion); B converted via cvt_pk. Prefetched.
// ---------------------------------------------------------------------------
__global__ __launch_bounds__(256) void outproj_v2_kernel(
    const u16* __restrict__ AO,
    const float* __restrict__ Wo, const float* __restrict__ bo,
    float* __restrict__ out)
{
    __shared__ __align__(16) u16 As[64][40];
    __shared__ __align__(16) u16 Bs[64][40];

    const int t    = threadIdx.x;
    const int wid  = t >> 6, lane = t & 63;
    const int m15  = lane & 15, quad = lane >> 4;
    const int wm   = wid >> 1, wn = wid & 1;
    const int bm   = blockIdx.x * 64;
    const int n0   = blockIdx.y * 64;

    const int lrow = t >> 2;        // 0..63
    const int lcol = (t & 3) * 8;   // 0,8,16,24

    const u16*   Ap = AO + (size_t)(bm + lrow) * 512 + lcol;
    const float* Bp = Wo + (size_t)(n0 + lrow) * 512 + lcol;
    uint4  areg = *(const uint4*)Ap;
    float4 b0 = *(const float4*)Bp, b1 = *(const float4*)(Bp + 4);

    f32x4 acc[2][2] = {};

    for (int k0 = 0; k0 < 512; k0 += 32) {
        __syncthreads();
        *(uint4*)(&As[lrow][lcol]) = areg;
        *(uint4*)(&Bs[lrow][lcol]) = pk8(b0, b1);
        __syncthreads();
        if (k0 + 32 < 512) {
            areg = *(const uint4*)(Ap + k0 + 32);
            b0 = *(const float4*)(Bp + k0 + 32); b1 = *(const float4*)(Bp + k0 + 36);
        }

        short8 afr[2], bfr[2];
#pragma unroll
        for (int mi = 0; mi < 2; ++mi)
            afr[mi] = *(const short8*)(&As[wm * 32 + mi * 16 + m15][quad * 8]);
#pragma unroll
        for (int ni = 0; ni < 2; ++ni)
            bfr[ni] = *(const short8*)(&Bs[wn * 32 + ni * 16 + m15][quad * 8]);
#pragma unroll
        for (int mi = 0; mi < 2; ++mi)
#pragma unroll
            for (int ni = 0; ni < 2; ++ni)
                acc[mi][ni] = __builtin_amdgcn_mfma_f32_16x16x32_bf16(
                    afr[mi], bfr[ni], acc[mi][ni], 0, 0, 0);
    }

#pragma unroll
    for (int mi = 0; mi < 2; ++mi)
#pragma unroll
        for (int ni = 0; ni < 2; ++ni) {
            const int col = n0 + wn * 32 + ni * 16 + m15;
            const float bv_ = bo[col];
#pragma unroll
            for (int r = 0; r < 4; ++r) {
                const int row = bm + wm * 32 + mi * 16 + quad * 4 + r;
                out[(size_t)row * 512 + col] = acc[mi][ni][r] + bv_;
            }
        }
}

// ---------------------------------------------------------------------------
// Fallback in-place fp32 output projection: AO = AO @ Wo^T + bo, (M,512).
// ---------------------------------------------------------------------------
__global__ __launch_bounds__(256) void outproj_inplace_kernel(
    float* __restrict__ AO,
    const float* __restrict__ Wo, const float* __restrict__ bo)
{
    __shared__ __align__(16) u16 As[32][520];
    __shared__ __align__(16) u16 Ws_[64][40];

    const int t    = threadIdx.x;
    const int wid  = t >> 6, lane = t & 63;
    const int m15  = lane & 15, quad = lane >> 4;
    const int wm   = wid >> 1, wn = wid & 1;
    const int bm   = blockIdx.x * 32;

#pragma unroll
    for (int it = 0; it < 8; ++it) {
        const int idx = t + it * 256;            // 0..2047
        const int row = idx >> 6, c8 = (idx & 63) * 8;
        stage8f(&As[row][c8], AO + (size_t)(bm + row) * 512 + c8);
    }
    const int lrow = t >> 2;
    const int lcol = (t & 3) * 8;
    __syncthreads();

    for (int n0 = 0; n0 < 512; n0 += 64) {
        f32x4 acc[2] = {};
        for (int k0 = 0; k0 < 512; k0 += 32) {
            __syncthreads();
            stage8f(&Ws_[lrow][lcol], Wo + (size_t)(n0 + lrow) * 512 + k0 + lcol);
            __syncthreads();
            const short8 afr = *(const short8*)(&As[wm * 16 + m15][k0 + quad * 8]);
#pragma unroll
            for (int ni = 0; ni < 2; ++ni) {
                const short8 bfr = *(const short8*)(&Ws_[wn * 32 + ni * 16 + m15][quad * 8]);
                acc[ni] = __builtin_amdgcn_mfma_f32_16x16x32_bf16(afr, bfr, acc[ni], 0, 0, 0);
            }
        }
#pragma unroll
        for (int ni = 0; ni < 2; ++ni) {
            const int col = n0 + wn * 32 + ni * 16 + m15;
            const float bv_ = bo[col];
#pragma unroll
            for (int r = 0; r < 4; ++r) {
                const int row = bm + wm * 16 + quad * 4 + r;
                AO[(size_t)row * 512 + col] = acc[ni][r] + bv_;
            }
        }
    }
}

extern "C" void kernel_launch(void* const* d_in, const int* in_sizes, int n_in,
                              void* d_out, int out_size, void* d_ws, size_t ws_size,
                              hipStream_t stream) {
    const float* x    = (const float*)d_in[0];
    const int*   mask = (const int*)d_in[1];
    const float* Wq = (const float*)d_in[2]; const float* bq = (const float*)d_in[3];
    const float* Wk = (const float*)d_in[4]; const float* bk = (const float*)d_in[5];
    const float* Wv = (const float*)d_in[6]; const float* bv = (const float*)d_in[7];
    const float* Wo = (const float*)d_in[8]; const float* bo = (const float*)d_in[9];

    float* out = (float*)d_out;
    u16*   ws  = (u16*)d_ws;

    const size_t per_bh   = (size_t)2 * L_ * 64 * 2;        // K+V bytes per bh
    const size_t kv_bytes = (size_t)BH_ * per_bh;           // 16 MiB
    const size_t ao_bytes = (size_t)M_ * 512 * 2;           // 8 MiB bf16 AO

    if (ws_size >= kv_bytes + ao_bytes) {
        // Primary: single chunk, bf16 AO in ws, N-split outproj.
        u16* Kws  = ws;
        u16* Vws  = Kws + (size_t)BH_ * (L_ * 64);
        u16* AOws = ws + kv_bytes / 2;                      // u16 elements
        kvproj_kernel<<<dim3(BH_, L_ / 64, 2), 256, 0, stream>>>(
            x, Wk, bk, Wv, bv, Kws, Vws, 0);
        attn_kernel<<<dim3(L_ / 128, BH_), 512, 0, stream>>>(
            x, Wq, bq, Kws, Vws, mask, out, AOws, 0);
        outproj_v2_kernel<<<dim3(M_ / 64, 8), 256, 0, stream>>>(AOws, Wo, bo, out);
    } else {
        // Fallback: chunked K/V, fp32 AO in d_out, in-place outproj.
        int chunk = 16;
        while (chunk > 1 && (size_t)chunk * per_bh > ws_size) chunk >>= 1;
        u16* Kws = ws;
        u16* Vws = Kws + (size_t)chunk * (L_ * 64);
        for (int bh0 = 0; bh0 < BH_; bh0 += chunk) {
            kvproj_kernel<<<dim3(chunk, L_ / 64, 2), 256, 0, stream>>>(
                x, Wk, bk, Wv, bv, Kws, Vws, bh0);
            attn_kernel<<<dim3(L_ / 128, chunk), 512, 0, stream>>>(
                x, Wq, bq, Kws, Vws, mask, out, nullptr, bh0);
        }
        outproj_inplace_kernel<<<dim3(M_ / 32), 256, 0, stream>>>(out, Wo, bo);
    }
}

// Round 4
// 250.543 us; speedup vs baseline: 1.6442x; 1.0838x over previous
//
#include <hip/hip_runtime.h>

// Round 19: 32x32x16 flash core, key-split streams, P fully in-register.
// - QK^T uses mfma_f32_32x32x16_bf16: A=K[32keys][16dims], B=Q^T[16][32q],
//   C[key][q] -> each lane owns one q-column (q = lane&31) -> softmax is
//   15 in-reg ops + 1 shfl_xor(32).
// - Waves 0-3 process keys 0..31 of every tile, waves 4-7 keys 32..63
//   (two flash streams per q-range); exact flash-combine merge at the end.
// - P->PV A-frags built in-register: 8 cvt_pk + 2 shfl_xor(32) + selects
//   per 16-key chunk. No P LDS round-trip.
// - Ks/Vts LDS pitch 64 with XOR slot swizzle (slot ^= row&7): conflict-free.
// kvproj/outproj unchanged from R18.

#define B_  2
#define L_  4096
#define D_  512
#define H_  8
#define BH_ 16
#define M_  8192

typedef __attribute__((ext_vector_type(8)))  short short8;   // 8 bf16
typedef __attribute__((ext_vector_type(4)))  float f32x4;
typedef __attribute__((ext_vector_type(16))) float f32x16;
typedef unsigned short u16;

#if __has_builtin(__builtin_amdgcn_exp2f)
#define EX2(x) __builtin_amdgcn_exp2f(x)
#else
#define EX2(x) exp2f(x)
#endif

static __device__ __forceinline__ u16 f2b(float f) {
    union { float f; unsigned i; } x; x.f = f;
    unsigned r = x.i + 0x7fff + ((x.i >> 16) & 1);   // RNE
    return (u16)(r >> 16);
}

static __device__ __forceinline__ unsigned cvt_pk_bf16(float lo, float hi) {
    unsigned r;
    asm("v_cvt_pk_bf16_f32 %0, %1, %2" : "=v"(r) : "v"(lo), "v"(hi));
    return r;
}

static __device__ __forceinline__ uint4 pk8(const float4& a, const float4& b) {
    uint4 o;
    o.x = cvt_pk_bf16(a.x, a.y);
    o.y = cvt_pk_bf16(a.z, a.w);
    o.z = cvt_pk_bf16(b.x, b.y);
    o.w = cvt_pk_bf16(b.z, b.w);
    return o;
}

static __device__ __forceinline__ void stage8f(u16* dst, const float* s) {
    const float4 a = *(const float4*)s;
    const float4 b = *(const float4*)(s + 4);
    *(uint4*)dst = pk8(a, b);
}

static __device__ __forceinline__ short8 mk8(unsigned a, unsigned b,
                                             unsigned c, unsigned d) {
    union { unsigned u[4]; short8 s; } x;
    x.u[0] = a; x.u[1] = b; x.u[2] = c; x.u[3] = d;
    return x.s;
}

// ---------------------------------------------------------------------------
// K/V projection (unchanged from R18).
// ---------------------------------------------------------------------------
__global__ __launch_bounds__(256) void kvproj_kernel(
    const float* __restrict__ x,
    const float* __restrict__ Wk, const float* __restrict__ bk,
    const float* __restrict__ Wv, const float* __restrict__ bv,
    u16* __restrict__ Kws, u16* __restrict__ Vws, int bh0)
{
    __shared__ __align__(16) unsigned char sm[10240];
    u16 (*As)[40] = (u16(*)[40])sm;
    u16 (*Bs)[40] = (u16(*)[40])(sm + 5120);
    u16 (*Ts)[73] = (u16(*)[73])sm;

    const int t    = threadIdx.x;
    const int wid  = t >> 6, lane = t & 63;
    const int m15  = lane & 15, quad = lane >> 4;
    const int wm   = wid >> 1, wn = wid & 1;

    const int bh = bh0 + blockIdx.x;
    const int b  = bh >> 3, h = bh & 7;
    const int l0 = blockIdx.y * 64;
    const float* W  = blockIdx.z ? Wv : Wk;
    const float* bi = blockIdx.z ? bv : bk;

    const int lrow = t >> 2;
    const int lcol = (t & 3) * 8;
    const size_t xrow0 = (size_t)b * L_ + l0;

    const float* Ap = x + (xrow0 + lrow) * 512 + lcol;
    const float* Bp = W + (size_t)(h * 64 + lrow) * 512 + lcol;
    float4 a0 = *(const float4*)(Ap), a1 = *(const float4*)(Ap + 4);
    float4 b0 = *(const float4*)(Bp), b1 = *(const float4*)(Bp + 4);

    f32x4 acc[2][2] = {};

    for (int k0 = 0; k0 < 512; k0 += 32) {
        __syncthreads();
        *(uint4*)(&As[lrow][lcol]) = pk8(a0, a1);
        *(uint4*)(&Bs[lrow][lcol]) = pk8(b0, b1);
        __syncthreads();
        if (k0 + 32 < 512) {
            a0 = *(const float4*)(Ap + k0 + 32); a1 = *(const float4*)(Ap + k0 + 36);
            b0 = *(const float4*)(Bp + k0 + 32); b1 = *(const float4*)(Bp + k0 + 36);
        }

        short8 afr[2], bfr[2];
#pragma unroll
        for (int mi = 0; mi < 2; ++mi)
            afr[mi] = *(const short8*)(&As[wm * 32 + mi * 16 + m15][quad * 8]);
#pragma unroll
        for (int ni = 0; ni < 2; ++ni)
            bfr[ni] = *(const short8*)(&Bs[wn * 32 + ni * 16 + m15][quad * 8]);
#pragma unroll
        for (int mi = 0; mi < 2; ++mi)
#pragma unroll
            for (int ni = 0; ni < 2; ++ni)
                acc[mi][ni] = __builtin_amdgcn_mfma_f32_16x16x32_bf16(
                    afr[mi], bfr[ni], acc[mi][ni], 0, 0, 0);
    }

    if (blockIdx.z == 0) {
        u16* out = Kws + (size_t)blockIdx.x * (L_ * 64);
#pragma unroll
        for (int mi = 0; mi < 2; ++mi)
#pragma unroll
            for (int ni = 0; ni < 2; ++ni) {
                const int d  = wn * 32 + ni * 16 + m15;
                const float bv_ = bi[h * 64 + d];
#pragma unroll
                for (int r = 0; r < 4; ++r) {
                    const int l = l0 + wm * 32 + mi * 16 + quad * 4 + r;
                    out[(size_t)l * 64 + d] = f2b(acc[mi][ni][r] + bv_);
                }
            }
    } else {
        __syncthreads();
#pragma unroll
        for (int mi = 0; mi < 2; ++mi)
#pragma unroll
            for (int ni = 0; ni < 2; ++ni) {
                const int d  = wn * 32 + ni * 16 + m15;
                const float bv_ = bi[h * 64 + d];
#pragma unroll
                for (int r = 0; r < 4; ++r)
                    Ts[wm * 32 + mi * 16 + quad * 4 + r][d] = f2b(acc[mi][ni][r] + bv_);
            }
        __syncthreads();
        u16* Vt = Vws + (size_t)blockIdx.x * ((size_t)64 * L_);
        const int d  = t >> 2;
        const int ls = (t & 3) * 16;
        u16 pk[16];
#pragma unroll
        for (int j = 0; j < 16; ++j) pk[j] = Ts[ls + j][d];
        u16* dst = Vt + (size_t)d * L_ + l0 + ls;
        *(uint4*)dst       = *(const uint4*)pk;
        *(uint4*)(dst + 8) = *(const uint4*)(pk + 8);
    }
}

// ---------------------------------------------------------------------------
// Fused Q-projection + flash attention, 32x32 core with key-split streams.
// grid (L/128, BH), block 512 (8 waves). Wave w: q-group (w&3) = q rows
// [32*(w&3), +32), key-stream kb = w>>2 (keys5 = 32*kb .. +32 of each tile).
// ---------------------------------------------------------------------------
// LDS map (phased):
//   phase1a: xs[128][40] @0 (10240), wqs[64][40] @10240 (5120)
//   phase1b: Qs[128][72] @0 (18432)
//   flash  : Ks[64][64] @0 (8192, XOR-swz), Vts[64][64] @8192 (8192, XOR-swz)
//            Msb[64]f32 @16384 (256), AlfR 8x32 f32 @16640 (1024)
//   merge  : Opart[64][128]f32 @0 (32768, swz), Mpart[2][128] @32768 (1024),
//            FA[128] @33792, FB[128] @34304 -> total 34816
__global__ __launch_bounds__(512, 4) void attn_kernel(
    const float* __restrict__ x,
    const float* __restrict__ Wq, const float* __restrict__ bq,
    const u16* __restrict__ Kws, const u16* __restrict__ Vws,
    const int* __restrict__ mask,
    float* __restrict__ O, u16* __restrict__ Obf, int bh0)
{
    __shared__ __align__(16) unsigned char sm[34816];
    u16 (*xs)[40]  = (u16(*)[40])sm;
    u16 (*wqs)[40] = (u16(*)[40])(sm + 10240);
    u16 (*Qs)[72]  = (u16(*)[72])sm;
    u16 (*Ks)[64]  = (u16(*)[64])sm;
    u16 (*Vts)[64] = (u16(*)[64])(sm + 8192);
    float* Msb     = (float*)(sm + 16384);

    const int t    = threadIdx.x;
    const int wid  = t >> 6, lane = t & 63;
    const int m15  = lane & 15, quad = lane >> 4;   // 16x16 phase-1 indices
    const int l5   = lane & 31, hi = lane >> 5;     // 32x32 flash indices
    const int hi4  = hi * 4;
    const int x7   = l5 & 7;
    const int qg   = wid & 3;                        // q-group
    const int kb   = wid >> 2;                       // key-stream (0 or 1)
    float* AlfR    = (float*)(sm + 16640) + wid * 32;

    const int bh = bh0 + blockIdx.y;
    const int b  = bh >> 3, h = bh & 7;
    const int q0 = blockIdx.x * 128;
    const u16* Kc  = Kws + (size_t)blockIdx.y * (L_ * 64);
    const u16* Vtc = Vws + (size_t)blockIdx.y * ((size_t)64 * L_);

    // staging map for flash tiles (64 rows x 64 cols, slot-swizzled)
    const int srow  = t >> 3;                        // 0..63
    const int scol8 = (t & 7);                       // 8-u16 slot index
    const int sslot = (scol8 ^ (srow & 7)) * 8;      // swizzled col base

    // issue first-tile global prefetch immediately (hides under phase 1)
    uint4 kreg = *(const uint4*)(Kc + (size_t)srow * 64 + scol8 * 8);
    uint4 vreg = *(const uint4*)(Vtc + (size_t)srow * L_ + scol8 * 8);
    int   mreg = (t < 64) ? mask[b * L_ + t] : 0;

    // ---- phase 1: Q[128][64] = x @ Wq[h]^T (+bq, *log2e/8 at pack time) ----
    f32x4 qacc[4] = {};
    {
        const int xr = t >> 2, xc = (t & 3) * 8;
        const float* xp = x + ((size_t)b * L_ + q0 + xr) * 512 + xc;
        const float* wp = Wq + (size_t)(h * 64 + xr) * 512 + xc;
        float4 xa0 = *(const float4*)xp, xa1 = *(const float4*)(xp + 4);
        float4 wa0 = {}, wa1 = {};
        if (t < 256) { wa0 = *(const float4*)wp; wa1 = *(const float4*)(wp + 4); }
        for (int k0 = 0; k0 < 512; k0 += 32) {
            __syncthreads();
            *(uint4*)(&xs[xr][xc]) = pk8(xa0, xa1);
            if (t < 256) *(uint4*)(&wqs[xr][xc]) = pk8(wa0, wa1);
            __syncthreads();
            if (k0 + 32 < 512) {
                xa0 = *(const float4*)(xp + k0 + 32); xa1 = *(const float4*)(xp + k0 + 36);
                if (t < 256) {
                    wa0 = *(const float4*)(wp + k0 + 32); wa1 = *(const float4*)(wp + k0 + 36);
                }
            }
            const short8 afr = *(const short8*)(&xs[wid * 16 + m15][quad * 8]);
#pragma unroll
            for (int ni = 0; ni < 4; ++ni) {
                const short8 bfr = *(const short8*)(&wqs[ni * 16 + m15][quad * 8]);
                qacc[ni] = __builtin_amdgcn_mfma_f32_16x16x32_bf16(afr, bfr, qacc[ni], 0, 0, 0);
            }
        }
    }

    // ---- phase 1b: bounce Q through LDS into 32x32 B-frags ----
    const float QSCALE = 0.125f * 1.44269504089f;    // /sqrt(dk) * log2(e)
    __syncthreads();                                  // xs reads done
#pragma unroll
    for (int ni = 0; ni < 4; ++ni) {
        const float bv_ = bq[h * 64 + ni * 16 + m15];
#pragma unroll
        for (int r = 0; r < 4; ++r)
            Qs[wid * 16 + quad * 4 + r][ni * 16 + m15] =
                f2b((qacc[ni][r] + bv_) * QSCALE);
    }
    __syncthreads();                                  // Qs complete
    short8 qfr[4];
#pragma unroll
    for (int kd = 0; kd < 4; ++kd)
        qfr[kd] = *(const short8*)(&Qs[32 * qg + l5][16 * kd + 8 * hi]);
    __syncthreads();                                  // Qs reads done

    // ---- flash loop: 64 tiles of 64 keys; this wave handles keys5 32*kb.. ----
    float m_i = -1e30f, l_i = 0.0f;                   // per lane: q = 32*qg + l5
    f32x16 oacc[2];
#pragma unroll
    for (int db = 0; db < 2; ++db)
#pragma unroll
        for (int e = 0; e < 16; ++e) oacc[db][e] = 0.0f;

    for (int kt = 0; kt < 64; ++kt) {
        __syncthreads();                              // prior tile reads done
        *(uint4*)(&Ks [srow][sslot]) = kreg;
        *(uint4*)(&Vts[srow][sslot]) = vreg;
        if (t < 64) Msb[t] = (mreg == 0) ? -14427.0f : 0.0f;
        __syncthreads();                              // tile visible
        if (kt + 1 < 64) {
            const int k1 = (kt + 1) * 64;
            kreg = *(const uint4*)(Kc + (size_t)(k1 + srow) * 64 + scol8 * 8);
            vreg = *(const uint4*)(Vtc + (size_t)srow * L_ + k1 + scol8 * 8);
            if (t < 64) mreg = mask[b * L_ + k1 + t];
        }

        // QK^T (log2-scaled), mask bias in C-init. C[key5][q]: lane q=l5,
        // rows key5 = (e&3) + 8*(e>>2) + 4*hi.
        f32x16 sa;
#pragma unroll
        for (int p = 0; p < 4; ++p) {
            const f32x4 bb = *(const f32x4*)(&Msb[32 * kb + 8 * p + hi4]);
            sa[4*p+0] = bb[0]; sa[4*p+1] = bb[1]; sa[4*p+2] = bb[2]; sa[4*p+3] = bb[3];
        }
#pragma unroll
        for (int kd = 0; kd < 4; ++kd) {
            const short8 kf = *(const short8*)(
                &Ks[32 * kb + l5][(((2 * kd + hi) ^ x7)) * 8]);
            sa = __builtin_amdgcn_mfma_f32_32x32x16_bf16(kf, qfr[kd], sa, 0, 0, 0);
        }

        // column max over this stream's 32 keys (pair lanes l5 / l5+32)
        float mx = fmaxf(
            fmaxf(fmaxf(fmaxf(sa[0], sa[1]),  fmaxf(sa[2], sa[3])),
                  fmaxf(fmaxf(sa[4], sa[5]),  fmaxf(sa[6], sa[7]))),
            fmaxf(fmaxf(fmaxf(sa[8], sa[9]),  fmaxf(sa[10], sa[11])),
                  fmaxf(fmaxf(sa[12], sa[13]), fmaxf(sa[14], sa[15]))));
        mx = fmaxf(mx, __shfl_xor(mx, 32));

        if (__any(mx > m_i)) {                        // exact defer-rescale
            const float mnew = fmaxf(m_i, mx);
            const float a = EX2(m_i - mnew);
            m_i = mnew;
            l_i *= a;
            if (hi == 0) AlfR[l5] = a;                // wave-local bounce
#pragma unroll
            for (int p = 0; p < 4; ++p) {
                const f32x4 a4 = *(const f32x4*)(&AlfR[8 * p + hi4]);
#pragma unroll
                for (int i = 0; i < 4; ++i) {
                    oacc[0][4*p+i] *= a4[i];
                    oacc[1][4*p+i] *= a4[i];
                }
            }
        }

        // P = exp2(S - m), in-register
        float pv[16];
#pragma unroll
        for (int r = 0; r < 16; ++r) pv[r] = EX2(sa[r] - m_i);
        float ss = ((pv[0]+pv[1]) + (pv[2]+pv[3])) + ((pv[4]+pv[5]) + (pv[6]+pv[7]))
                 + ((pv[8]+pv[9]) + (pv[10]+pv[11])) + ((pv[12]+pv[13]) + (pv[14]+pv[15]));
        ss += __shfl_xor(ss, 32);
        l_i += ss;

        // pack: W[m] = bf16x2(pv[2m], pv[2m+1]) -> keys5 8*(m>>1)+2*(m&1)+4*hi+{0,1}
        unsigned W[8];
#pragma unroll
        for (int m = 0; m < 8; ++m) W[m] = cvt_pk_bf16(pv[2*m], pv[2*m+1]);

        // PV: A = P[32q][16keys] chunks, B = V[16keys][32d] from Vts.
#pragma unroll
        for (int c1 = 0; c1 < 2; ++c1) {
            const unsigned X  = hi ? W[4*c1+0] : W[4*c1+2];  // value SENT to partner
            const unsigned Y  = hi ? W[4*c1+1] : W[4*c1+3];
            const unsigned Xp = __shfl_xor((int)X, 32);
            const unsigned Yp = __shfl_xor((int)Y, 32);
            const unsigned w0 = hi ? Xp : W[4*c1+0];
            const unsigned w1 = hi ? Yp : W[4*c1+1];
            const unsigned w2 = hi ? W[4*c1+2] : Xp;
            const unsigned w3 = hi ? W[4*c1+3] : Yp;
            const short8 af = mk8(w0, w1, w2, w3);
            const int kcg = 2 * kb + c1;              // global 16-key chunk
#pragma unroll
            for (int db = 0; db < 2; ++db) {
                const short8 vf = *(const short8*)(
                    &Vts[32 * db + l5][(((2 * kcg + hi) ^ x7)) * 8]);
                oacc[db] = __builtin_amdgcn_mfma_f32_32x32x16_bf16(af, vf, oacc[db], 0, 0, 0);
            }
        }
    }

    // ---- merge the two key-streams (exact flash-combine), write output ----
    float* Op  = (float*)sm;                 // [64][128] f32, slot-swizzled
    float* Mp0 = (float*)(sm + 32768);       // [128] m of stream B
    float* Mp1 = Mp0 + 128;                  // [128] l of stream B
    float* FA  = (float*)(sm + 33792);       // [128] factor for stream A
    float* FB  = FA + 128;                   // [128] factor for stream B

    __syncthreads();                          // flash loop fully done
    if (wid >= 4) {
#pragma unroll
        for (int db = 0; db < 2; ++db) {
            const int d = 32 * db + l5;
#pragma unroll
            for (int p = 0; p < 4; ++p) {
                const int qb   = 32 * qg + 8 * p + hi4;
                const int slot = (qb >> 2) ^ l5;
                f32x4 v;
#pragma unroll
                for (int i = 0; i < 4; ++i) v[i] = oacc[db][4*p+i];
                *(f32x4*)(&Op[d * 128 + slot * 4]) = v;
            }
        }
        if (hi == 0) { Mp0[32 * qg + l5] = m_i; Mp1[32 * qg + l5] = l_i; }
    }
    __syncthreads();
    if (wid < 4) {
        const int q5 = 32 * qg + l5;
        const float mB = Mp0[q5], lB = Mp1[q5];
        const float mS = fmaxf(m_i, mB);
        const float aA = EX2(m_i - mS), aB = EX2(mB - mS);
        const float linv = 1.0f / (l_i * aA + lB * aB);
        if (hi == 0) { FA[q5] = aA * linv; FB[q5] = aB * linv; }
#pragma unroll
        for (int db = 0; db < 2; ++db) {
            const int d = 32 * db + l5;
            const int col = h * 64 + d;
#pragma unroll
            for (int p = 0; p < 4; ++p) {
                const int qb   = 32 * qg + 8 * p + hi4;
                const f32x4 fa = *(const f32x4*)(&FA[qb]);
                const f32x4 fb = *(const f32x4*)(&FB[qb]);
                const int slot = (qb >> 2) ^ l5;
                const f32x4 ob = *(const f32x4*)(&Op[d * 128 + slot * 4]);
#pragma unroll
                for (int i = 0; i < 4; ++i) {
                    const float val = oacc[db][4*p+i] * fa[i] + ob[i] * fb[i];
                    const size_t row = (size_t)b * L_ + q0 + qb + i;
                    if (Obf) Obf[row * 512 + col] = f2b(val);
                    else     O  [row * 512 + col] = val;
                }
            }
        }
    }
}

// ---------------------------------------------------------------------------
// Output projection v2 (unchanged): out = AO(bf16) @ Wo^T + bo.
// ---------------------------------------------------------------------------
__global__ __launch_bounds__(256) void outproj_v2_kernel(
    const u16* __restrict__ AO,
    const float* __restrict__ Wo, const float* __restrict__ bo,
    float* __restrict__ out)
{
    __shared__ __align__(16) u16 As[64][40];
    __shared__ __align__(16) u16 Bs[64][40];

    const int t    = threadIdx.x;
    const int wid  = t >> 6, lane = t & 63;
    const int m15  = lane & 15, quad = lane >> 4;
    const int wm   = wid >> 1, wn = wid & 1;
    const int bm   = blockIdx.x * 64;
    const int n0   = blockIdx.y * 64;

    const int lrow = t >> 2;
    const int lcol = (t & 3) * 8;

    const u16*   Ap = AO + (size_t)(bm + lrow) * 512 + lcol;
    const float* Bp = Wo + (size_t)(n0 + lrow) * 512 + lcol;
    uint4  areg = *(const uint4*)Ap;
    float4 b0 = *(const float4*)Bp, b1 = *(const float4*)(Bp + 4);

    f32x4 acc[2][2] = {};

    for (int k0 = 0; k0 < 512; k0 += 32) {
        __syncthreads();
        *(uint4*)(&As[lrow][lcol]) = areg;
        *(uint4*)(&Bs[lrow][lcol]) = pk8(b0, b1);
        __syncthreads();
        if (k0 + 32 < 512) {
            areg = *(const uint4*)(Ap + k0 + 32);
            b0 = *(const float4*)(Bp + k0 + 32); b1 = *(const float4*)(Bp + k0 + 36);
        }

        short8 afr[2], bfr[2];
#pragma unroll
        for (int mi = 0; mi < 2; ++mi)
            afr[mi] = *(const short8*)(&As[wm * 32 + mi * 16 + m15][quad * 8]);
#pragma unroll
        for (int ni = 0; ni < 2; ++ni)
            bfr[ni] = *(const short8*)(&Bs[wn * 32 + ni * 16 + m15][quad * 8]);
#pragma unroll
        for (int mi = 0; mi < 2; ++mi)
#pragma unroll
            for (int ni = 0; ni < 2; ++ni)
                acc[mi][ni] = __builtin_amdgcn_mfma_f32_16x16x32_bf16(
                    afr[mi], bfr[ni], acc[mi][ni], 0, 0, 0);
    }

#pragma unroll
    for (int mi = 0; mi < 2; ++mi)
#pragma unroll
        for (int ni = 0; ni < 2; ++ni) {
            const int col = n0 + wn * 32 + ni * 16 + m15;
            const float bv_ = bo[col];
#pragma unroll
            for (int r = 0; r < 4; ++r) {
                const int row = bm + wm * 32 + mi * 16 + quad * 4 + r;
                out[(size_t)row * 512 + col] = acc[mi][ni][r] + bv_;
            }
        }
}

// ---------------------------------------------------------------------------
// Fallback in-place fp32 output projection (unchanged).
// ---------------------------------------------------------------------------
__global__ __launch_bounds__(256) void outproj_inplace_kernel(
    float* __restrict__ AO,
    const float* __restrict__ Wo, const float* __restrict__ bo)
{
    __shared__ __align__(16) u16 As[32][520];
    __shared__ __align__(16) u16 Ws_[64][40];

    const int t    = threadIdx.x;
    const int wid  = t >> 6, lane = t & 63;
    const int m15  = lane & 15, quad = lane >> 4;
    const int wm   = wid >> 1, wn = wid & 1;
    const int bm   = blockIdx.x * 32;

#pragma unroll
    for (int it = 0; it < 8; ++it) {
        const int idx = t + it * 256;
        const int row = idx >> 6, c8 = (idx & 63) * 8;
        stage8f(&As[row][c8], AO + (size_t)(bm + row) * 512 + c8);
    }
    const int lrow = t >> 2;
    const int lcol = (t & 3) * 8;
    __syncthreads();

    for (int n0 = 0; n0 < 512; n0 += 64) {
        f32x4 acc[2] = {};
        for (int k0 = 0; k0 < 512; k0 += 32) {
            __syncthreads();
            stage8f(&Ws_[lrow][lcol], Wo + (size_t)(n0 + lrow) * 512 + k0 + lcol);
            __syncthreads();
            const short8 afr = *(const short8*)(&As[wm * 16 + m15][k0 + quad * 8]);
#pragma unroll
            for (int ni = 0; ni < 2; ++ni) {
                const short8 bfr = *(const short8*)(&Ws_[wn * 32 + ni * 16 + m15][quad * 8]);
                acc[ni] = __builtin_amdgcn_mfma_f32_16x16x32_bf16(afr, bfr, acc[ni], 0, 0, 0);
            }
        }
#pragma unroll
        for (int ni = 0; ni < 2; ++ni) {
            const int col = n0 + wn * 32 + ni * 16 + m15;
            const float bv_ = bo[col];
#pragma unroll
            for (int r = 0; r < 4; ++r) {
                const int row = bm + wm * 16 + quad * 4 + r;
                AO[(size_t)row * 512 + col] = acc[ni][r] + bv_;
            }
        }
    }
}

extern "C" void kernel_launch(void* const* d_in, const int* in_sizes, int n_in,
                              void* d_out, int out_size, void* d_ws, size_t ws_size,
                              hipStream_t stream) {
    const float* x    = (const float*)d_in[0];
    const int*   mask = (const int*)d_in[1];
    const float* Wq = (const float*)d_in[2]; const float* bq = (const float*)d_in[3];
    const float* Wk = (const float*)d_in[4]; const float* bk = (const float*)d_in[5];
    const float* Wv = (const float*)d_in[6]; const float* bv = (const float*)d_in[7];
    const float* Wo = (const float*)d_in[8]; const float* bo = (const float*)d_in[9];

    float* out = (float*)d_out;
    u16*   ws  = (u16*)d_ws;

    const size_t per_bh   = (size_t)2 * L_ * 64 * 2;
    const size_t kv_bytes = (size_t)BH_ * per_bh;           // 16 MiB
    const size_t ao_bytes = (size_t)M_ * 512 * 2;           // 8 MiB

    if (ws_size >= kv_bytes + ao_bytes) {
        u16* Kws  = ws;
        u16* Vws  = Kws + (size_t)BH_ * (L_ * 64);
        u16* AOws = ws + kv_bytes / 2;
        kvproj_kernel<<<dim3(BH_, L_ / 64, 2), 256, 0, stream>>>(
            x, Wk, bk, Wv, bv, Kws, Vws, 0);
        attn_kernel<<<dim3(L_ / 128, BH_), 512, 0, stream>>>(
            x, Wq, bq, Kws, Vws, mask, out, AOws, 0);
        outproj_v2_kernel<<<dim3(M_ / 64, 8), 256, 0, stream>>>(AOws, Wo, bo, out);
    } else {
        int chunk = 16;
        while (chunk > 1 && (size_t)chunk * per_bh > ws_size) chunk >>= 1;
        u16* Kws = ws;
        u16* Vws = Kws + (size_t)chunk * (L_ * 64);
        for (int bh0 = 0; bh0 < BH_; bh0 += chunk) {
            kvproj_kernel<<<dim3(chunk, L_ / 64, 2), 256, 0, stream>>>(
                x, Wk, bk, Wv, bv, Kws, Vws, bh0);
            attn_kernel<<<dim3(L_ / 128, chunk), 512, 0, stream>>>(
                x, Wq, bq, Kws, Vws, mask, out, nullptr, bh0);
        }
        outproj_inplace_kernel<<<dim3(M_ / 32), 256, 0, stream>>>(out, Wo, bo);
    }
}

// Round 7
// 237.913 us; speedup vs baseline: 1.7315x; 1.0531x over previous
//
#include <hip/hip_runtime.h>

// Round 22: bisection. attn flash loop reverted VERBATIM to R19 (register
// prefetch staging, 2 barriers/tile — verified passing at 142us). Fused
// kvproj (K+V in one block) kept from R20/R21. If this passes, the gl16
// transport was the bug; if it fails, kvproj fusion is.

#define B_  2
#define L_  4096
#define D_  512
#define H_  8
#define BH_ 16
#define M_  8192

typedef __attribute__((ext_vector_type(8)))  short short8;   // 8 bf16
typedef __attribute__((ext_vector_type(4)))  float f32x4;
typedef __attribute__((ext_vector_type(16))) float f32x16;
typedef unsigned short u16;

#if __has_builtin(__builtin_amdgcn_exp2f)
#define EX2(x) __builtin_amdgcn_exp2f(x)
#else
#define EX2(x) exp2f(x)
#endif

static __device__ __forceinline__ u16 f2b(float f) {
    union { float f; unsigned i; } x; x.f = f;
    unsigned r = x.i + 0x7fff + ((x.i >> 16) & 1);   // RNE
    return (u16)(r >> 16);
}

static __device__ __forceinline__ unsigned cvt_pk_bf16(float lo, float hi) {
    unsigned r;
    asm("v_cvt_pk_bf16_f32 %0, %1, %2" : "=v"(r) : "v"(lo), "v"(hi));
    return r;
}

static __device__ __forceinline__ uint4 pk8(const float4& a, const float4& b) {
    uint4 o;
    o.x = cvt_pk_bf16(a.x, a.y);
    o.y = cvt_pk_bf16(a.z, a.w);
    o.z = cvt_pk_bf16(b.x, b.y);
    o.w = cvt_pk_bf16(b.z, b.w);
    return o;
}

static __device__ __forceinline__ void stage8f(u16* dst, const float* s) {
    const float4 a = *(const float4*)s;
    const float4 b = *(const float4*)(s + 4);
    *(uint4*)dst = pk8(a, b);
}

static __device__ __forceinline__ short8 mk8(unsigned a, unsigned b,
                                             unsigned c, unsigned d) {
    union { unsigned u[4]; short8 s; } x;
    x.u[0] = a; x.u[1] = b; x.u[2] = c; x.u[3] = d;
    return x.s;
}

// ---------------------------------------------------------------------------
// Fused K+V projection. grid (chunk, L/64), block 256 (4 waves, 2x2).
// ---------------------------------------------------------------------------
__global__ __launch_bounds__(256) void kvproj_kernel(
    const float* __restrict__ x,
    const float* __restrict__ Wk, const float* __restrict__ bk,
    const float* __restrict__ Wv, const float* __restrict__ bv,
    u16* __restrict__ Kws, u16* __restrict__ Vws, int bh0)
{
    __shared__ __align__(16) unsigned char sm[15360];
    u16 (*As)[40]  = (u16(*)[40])sm;            // 5120 B
    u16 (*Bks)[40] = (u16(*)[40])(sm + 5120);   // 5120 B
    u16 (*Bvs)[40] = (u16(*)[40])(sm + 10240);  // 5120 B
    u16 (*Ts)[73]  = (u16(*)[73])sm;            // 9344 B (V transpose bounce)

    const int t    = threadIdx.x;
    const int wid  = t >> 6, lane = t & 63;
    const int m15  = lane & 15, quad = lane >> 4;
    const int wm   = wid >> 1, wn = wid & 1;

    const int bh = bh0 + blockIdx.x;
    const int b  = bh >> 3, h = bh & 7;
    const int l0 = blockIdx.y * 64;

    const int lrow = t >> 2;        // 0..63
    const int lcol = (t & 3) * 8;   // 0,8,16,24

    const float* Ap  = x  + ((size_t)b * L_ + l0 + lrow) * 512 + lcol;
    const float* Bkp = Wk + (size_t)(h * 64 + lrow) * 512 + lcol;
    const float* Bvp = Wv + (size_t)(h * 64 + lrow) * 512 + lcol;
    float4 a0  = *(const float4*)Ap,  a1  = *(const float4*)(Ap + 4);
    float4 bk0 = *(const float4*)Bkp, bk1 = *(const float4*)(Bkp + 4);
    float4 bv0 = *(const float4*)Bvp, bv1 = *(const float4*)(Bvp + 4);

    f32x4 kacc[2][2] = {};
    f32x4 vacc[2][2] = {};

    for (int k0 = 0; k0 < 512; k0 += 32) {
        __syncthreads();
        *(uint4*)(&As [lrow][lcol]) = pk8(a0, a1);
        *(uint4*)(&Bks[lrow][lcol]) = pk8(bk0, bk1);
        *(uint4*)(&Bvs[lrow][lcol]) = pk8(bv0, bv1);
        __syncthreads();
        if (k0 + 32 < 512) {
            a0  = *(const float4*)(Ap  + k0 + 32); a1  = *(const float4*)(Ap  + k0 + 36);
            bk0 = *(const float4*)(Bkp + k0 + 32); bk1 = *(const float4*)(Bkp + k0 + 36);
            bv0 = *(const float4*)(Bvp + k0 + 32); bv1 = *(const float4*)(Bvp + k0 + 36);
        }

        short8 afr[2], bkf[2], bvf[2];
#pragma unroll
        for (int mi = 0; mi < 2; ++mi)
            afr[mi] = *(const short8*)(&As[wm * 32 + mi * 16 + m15][quad * 8]);
#pragma unroll
        for (int ni = 0; ni < 2; ++ni) {
            bkf[ni] = *(const short8*)(&Bks[wn * 32 + ni * 16 + m15][quad * 8]);
            bvf[ni] = *(const short8*)(&Bvs[wn * 32 + ni * 16 + m15][quad * 8]);
        }
#pragma unroll
        for (int mi = 0; mi < 2; ++mi)
#pragma unroll
            for (int ni = 0; ni < 2; ++ni) {
                kacc[mi][ni] = __builtin_amdgcn_mfma_f32_16x16x32_bf16(
                    afr[mi], bkf[ni], kacc[mi][ni], 0, 0, 0);
                vacc[mi][ni] = __builtin_amdgcn_mfma_f32_16x16x32_bf16(
                    afr[mi], bvf[ni], vacc[mi][ni], 0, 0, 0);
            }
    }

    // K epilogue: row-major L x 64
    {
        u16* out = Kws + (size_t)blockIdx.x * (L_ * 64);
#pragma unroll
        for (int mi = 0; mi < 2; ++mi)
#pragma unroll
            for (int ni = 0; ni < 2; ++ni) {
                const int d  = wn * 32 + ni * 16 + m15;
                const float bv_ = bk[h * 64 + d];
#pragma unroll
                for (int r = 0; r < 4; ++r) {
                    const int l = l0 + wm * 32 + mi * 16 + quad * 4 + r;
                    out[(size_t)l * 64 + d] = f2b(kacc[mi][ni][r] + bv_);
                }
            }
    }
    // V epilogue: transpose bounce -> 64 dims x L keys
    __syncthreads();   // all MFMA LDS reads done before Ts overwrite
#pragma unroll
    for (int mi = 0; mi < 2; ++mi)
#pragma unroll
        for (int ni = 0; ni < 2; ++ni) {
            const int d  = wn * 32 + ni * 16 + m15;
            const float bv_ = bv[h * 64 + d];
#pragma unroll
            for (int r = 0; r < 4; ++r)
                Ts[wm * 32 + mi * 16 + quad * 4 + r][d] = f2b(vacc[mi][ni][r] + bv_);
        }
    __syncthreads();
    {
        u16* Vt = Vws + (size_t)blockIdx.x * ((size_t)64 * L_);
        const int d  = t >> 2;
        const int ls = (t & 3) * 16;
        u16 pk[16];
#pragma unroll
        for (int j = 0; j < 16; ++j) pk[j] = Ts[ls + j][d];
        u16* dst = Vt + (size_t)d * L_ + l0 + ls;
        *(uint4*)dst       = *(const uint4*)pk;
        *(uint4*)(dst + 8) = *(const uint4*)(pk + 8);
    }
}

// ---------------------------------------------------------------------------
// Fused Q-projection + flash attention, 32x32 core with key-split streams.
// VERBATIM R19 (register-prefetch staging, 2 barriers/tile) — verified.
// ---------------------------------------------------------------------------
__global__ __launch_bounds__(512, 4) void attn_kernel(
    const float* __restrict__ x,
    const float* __restrict__ Wq, const float* __restrict__ bq,
    const u16* __restrict__ Kws, const u16* __restrict__ Vws,
    const int* __restrict__ mask,
    float* __restrict__ O, u16* __restrict__ Obf, int bh0)
{
    __shared__ __align__(16) unsigned char sm[34816];
    u16 (*xs)[40]  = (u16(*)[40])sm;
    u16 (*wqs)[40] = (u16(*)[40])(sm + 10240);
    u16 (*Qs)[72]  = (u16(*)[72])sm;
    u16 (*Ks)[64]  = (u16(*)[64])sm;
    u16 (*Vts)[64] = (u16(*)[64])(sm + 8192);
    float* Msb     = (float*)(sm + 16384);

    const int t    = threadIdx.x;
    const int wid  = t >> 6, lane = t & 63;
    const int m15  = lane & 15, quad = lane >> 4;   // 16x16 phase-1 indices
    const int l5   = lane & 31, hi = lane >> 5;     // 32x32 flash indices
    const int hi4  = hi * 4;
    const int x7   = l5 & 7;
    const int qg   = wid & 3;                        // q-group
    const int kb   = wid >> 2;                       // key-stream (0 or 1)
    float* AlfR    = (float*)(sm + 16640) + wid * 32;

    const int bh = bh0 + blockIdx.y;
    const int b  = bh >> 3, h = bh & 7;
    const int q0 = blockIdx.x * 128;
    const u16* Kc  = Kws + (size_t)blockIdx.y * (L_ * 64);
    const u16* Vtc = Vws + (size_t)blockIdx.y * ((size_t)64 * L_);

    // staging map for flash tiles (64 rows x 64 cols, slot-swizzled)
    const int srow  = t >> 3;                        // 0..63
    const int scol8 = (t & 7);                       // 8-u16 slot index
    const int sslot = (scol8 ^ (srow & 7)) * 8;      // swizzled col base

    // issue first-tile global prefetch immediately (hides under phase 1)
    uint4 kreg = *(const uint4*)(Kc + (size_t)srow * 64 + scol8 * 8);
    uint4 vreg = *(const uint4*)(Vtc + (size_t)srow * L_ + scol8 * 8);
    int   mreg = (t < 64) ? mask[b * L_ + t] : 0;

    // ---- phase 1: Q[128][64] = x @ Wq[h]^T (+bq, *log2e/8 at pack time) ----
    f32x4 qacc[4] = {};
    {
        const int xr = t >> 2, xc = (t & 3) * 8;
        const float* xp = x + ((size_t)b * L_ + q0 + xr) * 512 + xc;
        const float* wp = Wq + (size_t)(h * 64 + xr) * 512 + xc;
        float4 xa0 = *(const float4*)xp, xa1 = *(const float4*)(xp + 4);
        float4 wa0 = {}, wa1 = {};
        if (t < 256) { wa0 = *(const float4*)wp; wa1 = *(const float4*)(wp + 4); }
        for (int k0 = 0; k0 < 512; k0 += 32) {
            __syncthreads();
            *(uint4*)(&xs[xr][xc]) = pk8(xa0, xa1);
            if (t < 256) *(uint4*)(&wqs[xr][xc]) = pk8(wa0, wa1);
            __syncthreads();
            if (k0 + 32 < 512) {
                xa0 = *(const float4*)(xp + k0 + 32); xa1 = *(const float4*)(xp + k0 + 36);
                if (t < 256) {
                    wa0 = *(const float4*)(wp + k0 + 32); wa1 = *(const float4*)(wp + k0 + 36);
                }
            }
            const short8 afr = *(const short8*)(&xs[wid * 16 + m15][quad * 8]);
#pragma unroll
            for (int ni = 0; ni < 4; ++ni) {
                const short8 bfr = *(const short8*)(&wqs[ni * 16 + m15][quad * 8]);
                qacc[ni] = __builtin_amdgcn_mfma_f32_16x16x32_bf16(afr, bfr, qacc[ni], 0, 0, 0);
            }
        }
    }

    // ---- phase 1b: bounce Q through LDS into 32x32 B-frags ----
    const float QSCALE = 0.125f * 1.44269504089f;    // /sqrt(dk) * log2(e)
    __syncthreads();                                  // xs reads done
#pragma unroll
    for (int ni = 0; ni < 4; ++ni) {
        const float bv_ = bq[h * 64 + ni * 16 + m15];
#pragma unroll
        for (int r = 0; r < 4; ++r)
            Qs[wid * 16 + quad * 4 + r][ni * 16 + m15] =
                f2b((qacc[ni][r] + bv_) * QSCALE);
    }
    __syncthreads();                                  // Qs complete
    short8 qfr[4];
#pragma unroll
    for (int kd = 0; kd < 4; ++kd)
        qfr[kd] = *(const short8*)(&Qs[32 * qg + l5][16 * kd + 8 * hi]);
    __syncthreads();                                  // Qs reads done

    // ---- flash loop: 64 tiles of 64 keys; this wave handles keys5 32*kb.. ----
    float m_i = -1e30f, l_i = 0.0f;                   // per lane: q = 32*qg + l5
    f32x16 oacc[2];
#pragma unroll
    for (int db = 0; db < 2; ++db)
#pragma unroll
        for (int e = 0; e < 16; ++e) oacc[db][e] = 0.0f;

    for (int kt = 0; kt < 64; ++kt) {
        __syncthreads();                              // prior tile reads done
        *(uint4*)(&Ks [srow][sslot]) = kreg;
        *(uint4*)(&Vts[srow][sslot]) = vreg;
        if (t < 64) Msb[t] = (mreg == 0) ? -14427.0f : 0.0f;
        __syncthreads();                              // tile visible
        if (kt + 1 < 64) {
            const int k1 = (kt + 1) * 64;
            kreg = *(const uint4*)(Kc + (size_t)(k1 + srow) * 64 + scol8 * 8);
            vreg = *(const uint4*)(Vtc + (size_t)srow * L_ + k1 + scol8 * 8);
            if (t < 64) mreg = mask[b * L_ + k1 + t];
        }

        // QK^T (log2-scaled), mask bias in C-init. C[key5][q]: lane q=l5,
        // rows key5 = (e&3) + 8*(e>>2) + 4*hi.
        f32x16 sa;
#pragma unroll
        for (int p = 0; p < 4; ++p) {
            const f32x4 bb = *(const f32x4*)(&Msb[32 * kb + 8 * p + hi4]);
            sa[4*p+0] = bb[0]; sa[4*p+1] = bb[1]; sa[4*p+2] = bb[2]; sa[4*p+3] = bb[3];
        }
#pragma unroll
        for (int kd = 0; kd < 4; ++kd) {
            const short8 kf = *(const short8*)(
                &Ks[32 * kb + l5][(((2 * kd + hi) ^ x7)) * 8]);
            sa = __builtin_amdgcn_mfma_f32_32x32x16_bf16(kf, qfr[kd], sa, 0, 0, 0);
        }

        // column max over this stream's 32 keys (pair lanes l5 / l5+32)
        float mx = fmaxf(
            fmaxf(fmaxf(fmaxf(sa[0], sa[1]),  fmaxf(sa[2], sa[3])),
                  fmaxf(fmaxf(sa[4], sa[5]),  fmaxf(sa[6], sa[7]))),
            fmaxf(fmaxf(fmaxf(sa[8], sa[9]),  fmaxf(sa[10], sa[11])),
                  fmaxf(fmaxf(sa[12], sa[13]), fmaxf(sa[14], sa[15]))));
        mx = fmaxf(mx, __shfl_xor(mx, 32));

        if (__any(mx > m_i)) {                        // exact defer-rescale
            const float mnew = fmaxf(m_i, mx);
            const float a = EX2(m_i - mnew);
            m_i = mnew;
            l_i *= a;
            if (hi == 0) AlfR[l5] = a;                // wave-local bounce
#pragma unroll
            for (int p = 0; p < 4; ++p) {
                const f32x4 a4 = *(const f32x4*)(&AlfR[8 * p + hi4]);
#pragma unroll
                for (int i = 0; i < 4; ++i) {
                    oacc[0][4*p+i] *= a4[i];
                    oacc[1][4*p+i] *= a4[i];
                }
            }
        }

        // P = exp2(S - m), in-register
        float pv[16];
#pragma unroll
        for (int r = 0; r < 16; ++r) pv[r] = EX2(sa[r] - m_i);
        float ss = ((pv[0]+pv[1]) + (pv[2]+pv[3])) + ((pv[4]+pv[5]) + (pv[6]+pv[7]))
                 + ((pv[8]+pv[9]) + (pv[10]+pv[11])) + ((pv[12]+pv[13]) + (pv[14]+pv[15]));
        ss += __shfl_xor(ss, 32);
        l_i += ss;

        // pack: W[m] = bf16x2(pv[2m], pv[2m+1])
        unsigned W[8];
#pragma unroll
        for (int m = 0; m < 8; ++m) W[m] = cvt_pk_bf16(pv[2*m], pv[2*m+1]);

        // PV: A = P[32q][16keys] chunks, B = V[16keys][32d] from Vts.
#pragma unroll
        for (int c1 = 0; c1 < 2; ++c1) {
            const unsigned X  = hi ? W[4*c1+0] : W[4*c1+2];  // value SENT to partner
            const unsigned Y  = hi ? W[4*c1+1] : W[4*c1+3];
            const unsigned Xp = __shfl_xor((int)X, 32);
            const unsigned Yp = __shfl_xor((int)Y, 32);
            const unsigned w0 = hi ? Xp : W[4*c1+0];
            const unsigned w1 = hi ? Yp : W[4*c1+1];
            const unsigned w2 = hi ? W[4*c1+2] : Xp;
            const unsigned w3 = hi ? W[4*c1+3] : Yp;
            const short8 af = mk8(w0, w1, w2, w3);
            const int kcg = 2 * kb + c1;              // global 16-key chunk
#pragma unroll
            for (int db = 0; db < 2; ++db) {
                const short8 vf = *(const short8*)(
                    &Vts[32 * db + l5][(((2 * kcg + hi) ^ x7)) * 8]);
                oacc[db] = __builtin_amdgcn_mfma_f32_32x32x16_bf16(af, vf, oacc[db], 0, 0, 0);
            }
        }
    }

    // ---- merge the two key-streams (exact flash-combine), write output ----
    float* Op  = (float*)sm;                 // [64][128] f32, slot-swizzled
    float* Mp0 = (float*)(sm + 32768);       // [128] m of stream B
    float* Mp1 = Mp0 + 128;                  // [128] l of stream B
    float* FA  = (float*)(sm + 33792);       // [128] factor for stream A
    float* FB  = FA + 128;                   // [128] factor for stream B

    __syncthreads();                          // flash loop fully done
    if (wid >= 4) {
#pragma unroll
        for (int db = 0; db < 2; ++db) {
            const int d = 32 * db + l5;
#pragma unroll
            for (int p = 0; p < 4; ++p) {
                const int qb   = 32 * qg + 8 * p + hi4;
                const int slot = (qb >> 2) ^ l5;
                f32x4 v;
#pragma unroll
                for (int i = 0; i < 4; ++i) v[i] = oacc[db][4*p+i];
                *(f32x4*)(&Op[d * 128 + slot * 4]) = v;
            }
        }
        if (hi == 0) { Mp0[32 * qg + l5] = m_i; Mp1[32 * qg + l5] = l_i; }
    }
    __syncthreads();
    if (wid < 4) {
        const int q5 = 32 * qg + l5;
        const float mB = Mp0[q5], lB = Mp1[q5];
        const float mS = fmaxf(m_i, mB);
        const float aA = EX2(m_i - mS), aB = EX2(mB - mS);
        const float linv = 1.0f / (l_i * aA + lB * aB);
        if (hi == 0) { FA[q5] = aA * linv; FB[q5] = aB * linv; }
#pragma unroll
        for (int db = 0; db < 2; ++db) {
            const int d = 32 * db + l5;
            const int col = h * 64 + d;
#pragma unroll
            for (int p = 0; p < 4; ++p) {
                const int qb   = 32 * qg + 8 * p + hi4;
                const f32x4 fa = *(const f32x4*)(&FA[qb]);
                const f32x4 fb = *(const f32x4*)(&FB[qb]);
                const int slot = (qb >> 2) ^ l5;
                const f32x4 ob = *(const f32x4*)(&Op[d * 128 + slot * 4]);
#pragma unroll
                for (int i = 0; i < 4; ++i) {
                    const float val = oacc[db][4*p+i] * fa[i] + ob[i] * fb[i];
                    const size_t row = (size_t)b * L_ + q0 + qb + i;
                    if (Obf) Obf[row * 512 + col] = f2b(val);
                    else     O  [row * 512 + col] = val;
                }
            }
        }
    }
}

// ---------------------------------------------------------------------------
// Output projection v2 (unchanged): out = AO(bf16) @ Wo^T + bo.
// ---------------------------------------------------------------------------
__global__ __launch_bounds__(256) void outproj_v2_kernel(
    const u16* __restrict__ AO,
    const float* __restrict__ Wo, const float* __restrict__ bo,
    float* __restrict__ out)
{
    __shared__ __align__(16) u16 As[64][40];
    __shared__ __align__(16) u16 Bs[64][40];

    const int t    = threadIdx.x;
    const int wid  = t >> 6, lane = t & 63;
    const int m15  = lane & 15, quad = lane >> 4;
    const int wm   = wid >> 1, wn = wid & 1;
    const int bm   = blockIdx.x * 64;
    const int n0   = blockIdx.y * 64;

    const int lrow = t >> 2;
    const int lcol = (t & 3) * 8;

    const u16*   Ap = AO + (size_t)(bm + lrow) * 512 + lcol;
    const float* Bp = Wo + (size_t)(n0 + lrow) * 512 + lcol;
    uint4  areg = *(const uint4*)Ap;
    float4 b0 = *(const float4*)Bp, b1 = *(const float4*)(Bp + 4);

    f32x4 acc[2][2] = {};

    for (int k0 = 0; k0 < 512; k0 += 32) {
        __syncthreads();
        *(uint4*)(&As[lrow][lcol]) = areg;
        *(uint4*)(&Bs[lrow][lcol]) = pk8(b0, b1);
        __syncthreads();
        if (k0 + 32 < 512) {
            areg = *(const uint4*)(Ap + k0 + 32);
            b0 = *(const float4*)(Bp + k0 + 32); b1 = *(const float4*)(Bp + k0 + 36);
        }

        short8 afr[2], bfr[2];
#pragma unroll
        for (int mi = 0; mi < 2; ++mi)
            afr[mi] = *(const short8*)(&As[wm * 32 + mi * 16 + m15][quad * 8]);
#pragma unroll
        for (int ni = 0; ni < 2; ++ni)
            bfr[ni] = *(const short8*)(&Bs[wn * 32 + ni * 16 + m15][quad * 8]);
#pragma unroll
        for (int mi = 0; mi < 2; ++mi)
#pragma unroll
            for (int ni = 0; ni < 2; ++ni)
                acc[mi][ni] = __builtin_amdgcn_mfma_f32_16x16x32_bf16(
                    afr[mi], bfr[ni], acc[mi][ni], 0, 0, 0);
    }

#pragma unroll
    for (int mi = 0; mi < 2; ++mi)
#pragma unroll
        for (int ni = 0; ni < 2; ++ni) {
            const int col = n0 + wn * 32 + ni * 16 + m15;
            const float bv_ = bo[col];
#pragma unroll
            for (int r = 0; r < 4; ++r) {
                const int row = bm + wm * 32 + mi * 16 + quad * 4 + r;
                out[(size_t)row * 512 + col] = acc[mi][ni][r] + bv_;
            }
        }
}

// ---------------------------------------------------------------------------
// Fallback in-place fp32 output projection (unchanged).
// ---------------------------------------------------------------------------
__global__ __launch_bounds__(256) void outproj_inplace_kernel(
    float* __restrict__ AO,
    const float* __restrict__ Wo, const float* __restrict__ bo)
{
    __shared__ __align__(16) u16 As[32][520];
    __shared__ __align__(16) u16 Ws_[64][40];

    const int t    = threadIdx.x;
    const int wid  = t >> 6, lane = t & 63;
    const int m15  = lane & 15, quad = lane >> 4;
    const int wm   = wid >> 1, wn = wid & 1;
    const int bm   = blockIdx.x * 32;

#pragma unroll
    for (int it = 0; it < 8; ++it) {
        const int idx = t + it * 256;
        const int row = idx >> 6, c8 = (idx & 63) * 8;
        stage8f(&As[row][c8], AO + (size_t)(bm + row) * 512 + c8);
    }
    const int lrow = t >> 2;
    const int lcol = (t & 3) * 8;
    __syncthreads();

    for (int n0 = 0; n0 < 512; n0 += 64) {
        f32x4 acc[2] = {};
        for (int k0 = 0; k0 < 512; k0 += 32) {
            __syncthreads();
            stage8f(&Ws_[lrow][lcol], Wo + (size_t)(n0 + lrow) * 512 + k0 + lcol);
            __syncthreads();
            const short8 afr = *(const short8*)(&As[wm * 16 + m15][k0 + quad * 8]);
#pragma unroll
            for (int ni = 0; ni < 2; ++ni) {
                const short8 bfr = *(const short8*)(&Ws_[wn * 32 + ni * 16 + m15][quad * 8]);
                acc[ni] = __builtin_amdgcn_mfma_f32_16x16x32_bf16(afr, bfr, acc[ni], 0, 0, 0);
            }
        }
#pragma unroll
        for (int ni = 0; ni < 2; ++ni) {
            const int col = n0 + wn * 32 + ni * 16 + m15;
            const float bv_ = bo[col];
#pragma unroll
            for (int r = 0; r < 4; ++r) {
                const int row = bm + wm * 16 + quad * 4 + r;
                AO[(size_t)row * 512 + col] = acc[ni][r] + bv_;
            }
        }
    }
}

extern "C" void kernel_launch(void* const* d_in, const int* in_sizes, int n_in,
                              void* d_out, int out_size, void* d_ws, size_t ws_size,
                              hipStream_t stream) {
    const float* x    = (const float*)d_in[0];
    const int*   mask = (const int*)d_in[1];
    const float* Wq = (const float*)d_in[2]; const float* bq = (const float*)d_in[3];
    const float* Wk = (const float*)d_in[4]; const float* bk = (const float*)d_in[5];
    const float* Wv = (const float*)d_in[6]; const float* bv = (const float*)d_in[7];
    const float* Wo = (const float*)d_in[8]; const float* bo = (const float*)d_in[9];

    float* out = (float*)d_out;
    u16*   ws  = (u16*)d_ws;

    const size_t per_bh   = (size_t)2 * L_ * 64 * 2;
    const size_t kv_bytes = (size_t)BH_ * per_bh;           // 16 MiB
    const size_t ao_bytes = (size_t)M_ * 512 * 2;           // 8 MiB

    if (ws_size >= kv_bytes + ao_bytes) {
        u16* Kws  = ws;
        u16* Vws  = Kws + (size_t)BH_ * (L_ * 64);
        u16* AOws = ws + kv_bytes / 2;
        kvproj_kernel<<<dim3(BH_, L_ / 64), 256, 0, stream>>>(
            x, Wk, bk, Wv, bv, Kws, Vws, 0);
        attn_kernel<<<dim3(L_ / 128, BH_), 512, 0, stream>>>(
            x, Wq, bq, Kws, Vws, mask, out, AOws, 0);
        outproj_v2_kernel<<<dim3(M_ / 64, 8), 256, 0, stream>>>(AOws, Wo, bo, out);
    } else {
        int chunk = 16;
        while (chunk > 1 && (size_t)chunk * per_bh > ws_size) chunk >>= 1;
        u16* Kws = ws;
        u16* Vws = Kws + (size_t)chunk * (L_ * 64);
        for (int bh0 = 0; bh0 < BH_; bh0 += chunk) {
            kvproj_kernel<<<dim3(chunk, L_ / 64), 256, 0, stream>>>(
                x, Wk, bk, Wv, bv, Kws, Vws, bh0);
            attn_kernel<<<dim3(L_ / 128, chunk), 512, 0, stream>>>(
                x, Wq, bq, Kws, Vws, mask, out, nullptr, bh0);
        }
        outproj_inplace_kernel<<<dim3(M_ / 32), 256, 0, stream>>>(out, Wo, bo);
    }
}